// Round 5
// baseline (728.630 us; speedup 1.0000x reference)
//
#include <hip/hip_runtime.h>
#include <hip/hip_bf16.h>
#include <cmath>

// Problem constants
#define B_SZ 8
#define L_SZ 2048
#define D_SZ 1024
#define CH 341
#define CP 384               // padded channel dim (24 x 16)
#define LCONV 2046           // L - KERNEL + 1
#define NSEG 512
#define KDIM 3072            // 3 * 1024 folded conv K
#define KSTEPS 48            // KDIM / 64

#define POOLED_N (B_SZ * NSEG * D_SZ)

typedef _Float16 f16x8 __attribute__((ext_vector_type(8)));
typedef float f32x4 __attribute__((ext_vector_type(4)));

__device__ __forceinline__ void gl_lds16(const void* g, void* l) {
    __builtin_amdgcn_global_load_lds(
        (const __attribute__((address_space(1))) unsigned int*)g,
        (__attribute__((address_space(3))) unsigned int*)l, 16, 0, 0);
}

// ---------------------------------------------------------------------------
// Convert hidden fp32 -> fp16 (single copy; fixup kernel guarantees sign
// correctness of thresholded logits, so one fp16 pass suffices)
// ---------------------------------------------------------------------------
__global__ __launch_bounds__(256) void convert_hidden_kernel(
        const float* __restrict__ hidden, _Float16* __restrict__ hid16) {
    size_t idx = (size_t)blockIdx.x * 256 + threadIdx.x;   // 8 elems / thread
    float4 v0 = ((const float4*)hidden)[idx * 2];
    float4 v1 = ((const float4*)hidden)[idx * 2 + 1];
    f16x8 o;
    o[0] = (_Float16)v0.x; o[1] = (_Float16)v0.y;
    o[2] = (_Float16)v0.z; o[3] = (_Float16)v0.w;
    o[4] = (_Float16)v1.x; o[5] = (_Float16)v1.y;
    o[6] = (_Float16)v1.z; o[7] = (_Float16)v1.w;
    ((f16x8*)hid16)[idx] = o;
}

// ---------------------------------------------------------------------------
// Convert w1 (Ch,D,K) -> bfrag in EXACT MFMA B-fragment order:
//   flat f16 index fo = (((tt*48 + s)*2 + kc)*64 + lane)*8 + j
//   content: channel c = tt*16 + (lane&15)
//            k         = s*64 + kc*32 + ((lane>>4)<<3) + j   (k' = kk*1024+d)
// so a wave's per-step B fragment is one contiguous 1 KB global_load_dwordx4.
// c padded to 384 with zeros. Also init logits to b2.
// ---------------------------------------------------------------------------
__global__ __launch_bounds__(256) void convert_w1_kernel(
        const float* __restrict__ w1, const float* __restrict__ b2,
        _Float16* __restrict__ bfrag, float* __restrict__ logits) {
    int idx = blockIdx.x * 256 + threadIdx.x;   // < 384*3072
    int j = idx & 7;
    int lane = (idx >> 3) & 63;
    int kc = (idx >> 9) & 1;
    int rest = idx >> 10;
    int s = rest % KSTEPS;
    int tt = rest / KSTEPS;
    int c = tt * 16 + (lane & 15);
    int k = s * 64 + kc * 32 + ((lane >> 4) << 3) + j;
    int kk = k >> 10, d = k & 1023;
    float v = (c < CH) ? w1[((size_t)c * 1024 + d) * 3 + kk] : 0.0f;
    bfrag[idx] = (_Float16)v;
    if (idx < B_SZ * LCONV) logits[idx] = b2[0];
}

// ---------------------------------------------------------------------------
// fp16 MFMA conv GEMM, B-in-registers, 3-deep counted-vmcnt pipeline (T3/T4).
// (Unchanged from R4 — serves as the control for this round's tail fix.
//  R2/R3/R4 triangulated: ~58-60 us is a per-CU VMEM-throughput limit of
//  this tile shape, insensitive to pipeline depth / drain / wave count.)
// ---------------------------------------------------------------------------
#define LDS_BUF 8192         // one A buffer

#define WAITV8() asm volatile("s_waitcnt vmcnt(8)" ::: "memory")
#define WAITV0() asm volatile("s_waitcnt vmcnt(0)" ::: "memory")
#define BAR()    __builtin_amdgcn_s_barrier()

#define LOAD_B(DST) do {                                                    \
    _Pragma("unroll")                                                       \
    for (int jj = 0; jj < 3; ++jj) {                                        \
        DST[jj][0] = bptr[jj][0];                                           \
        DST[jj][1] = bptr[jj][64];                                          \
        bptr[jj] += 128;                                                    \
    } } while (0)

#define ISSUE_A(OFF) do {                                                   \
    gl_lds16(pa0, lds + (OFF) + (wave * 64) * 16);                          \
    gl_lds16(pa1, lds + (OFF) + (256 + wave * 64) * 16);                    \
    pa0 += 64; pa1 += 64; } while (0)

#define COMPUTE(OFF, BSET) do {                                             \
    _Pragma("unroll")                                                       \
    for (int kc = 0; kc < 2; ++kc) {                                        \
        f16x8 a[4];                                                         \
        _Pragma("unroll")                                                   \
        for (int ii = 0; ii < 4; ++ii)                                      \
            a[ii] = *(const f16x8*)(lds + (OFF) + (kc * 256 + ii * 64 + lane) * 16); \
        _Pragma("unroll")                                                   \
        for (int ii = 0; ii < 4; ++ii)                                      \
            _Pragma("unroll")                                               \
            for (int jj = 0; jj < 3; ++jj)                                  \
                acc[ii][jj] = __builtin_amdgcn_mfma_f32_16x16x32_f16(       \
                    a[ii], BSET[jj][kc], acc[ii][jj], 0, 0, 0);             \
    } } while (0)

__global__ __launch_bounds__(256, 2) void conv_mfma_kernel(
        const _Float16* __restrict__ hid16, const _Float16* __restrict__ bfrag,
        const float* __restrict__ b1, const float* __restrict__ w2,
        float* __restrict__ logits) {
    const int nt = blockIdx.x;           // 0..1
    const int mt = blockIdx.y;           // 0..31
    const int b  = blockIdx.z;
    const int l0 = mt * 64;
    const int n0 = nt * 192;
    const int tid = threadIdx.x;
    const int wave = tid >> 6, lane = tid & 63;
    const int wn = wave;                 // 1x4 wave grid: wave = channel strip
    const int quad = lane >> 4, l16 = lane & 15;

    __shared__ __align__(16) char lds[3 * LDS_BUF];   // 24 KB: 3 x A 8K

    const _Float16* hb = hid16 + (size_t)b * L_SZ * D_SZ;

    // A staging source pointers: 512 entries (2 kc x 256), 2 per thread.
    const _Float16* pa0;
    const _Float16* pa1;
    {
        int f0 = tid;                    // kc=0 half
        int m0 = ((f0 >> 6) << 4) + (f0 & 15);
        int k0 = ((f0 >> 4) & 3) * 8;
        int l = l0 + m0; if (l > LCONV - 1) l = LCONV - 1;
        pa0 = hb + (size_t)l * 1024 + k0;
        int f1 = tid;                    // kc=1 half
        int m1 = ((f1 >> 6) << 4) + (f1 & 15);
        int k1 = ((f1 >> 4) & 3) * 8;
        l = l0 + m1; if (l > LCONV - 1) l = LCONV - 1;
        pa1 = hb + (size_t)l * 1024 + 32 + k1;
    }

    // B fragment pointers: one per jj, advancing 128 f16x8-units (2 KB) / step.
    const f16x8* bp = (const f16x8*)bfrag;
    const f16x8* bptr[3];
    #pragma unroll
    for (int jj = 0; jj < 3; ++jj) {
        int tt = nt * 12 + wn * 3 + jj;
        bptr[jj] = bp + (size_t)tt * (KSTEPS * 2 * 64) + lane;
    }

    f32x4 acc[4][3] = {};
    f16x8 B0[3][2], B1[3][2], B2[3][2];

    // ---- prologue: batches 0 and 1 in flight (8 VMEM each) ----
    LOAD_B(B0); ISSUE_A(0);
    LOAD_B(B1); ISSUE_A(LDS_BUF);

    // steps 0..44, unrolled by 3 (buffer/set rotation is compile-time)
    for (int t = 0; t < 15; ++t) {
        WAITV8(); BAR();                 // batch 3t retired; 3t+1 in flight
        LOAD_B(B2); ISSUE_A(2 * LDS_BUF);  // issue batch 3t+2
        COMPUTE(0, B0);                  // compute step 3t

        WAITV8(); BAR();                 // batch 3t+1 retired
        LOAD_B(B0); ISSUE_A(0);          // issue batch 3t+3
        COMPUTE(LDS_BUF, B1);            // compute step 3t+1

        WAITV8(); BAR();                 // batch 3t+2 retired
        LOAD_B(B1); ISSUE_A(LDS_BUF);    // issue batch 3t+4
        COMPUTE(2 * LDS_BUF, B2);        // compute step 3t+2
    }
    // tail: steps 45,46,47 (batches 45,46 in flight; 47 not yet issued)
    WAITV8(); BAR();                     // batch 45 retired
    LOAD_B(B2); ISSUE_A(2 * LDS_BUF);    // issue batch 47
    COMPUTE(0, B0);                      // step 45
    WAITV8(); BAR();                     // batch 46 retired
    COMPUTE(LDS_BUF, B1);                // step 46
    WAITV0(); BAR();                     // batch 47 retired
    COMPUTE(2 * LDS_BUF, B2);            // step 47

    __syncthreads();          // before reusing lds as reduction scratch

    // --- epilogue: relu(acc + b1)*w2, reduce over c, atomic into logits ---
    float cb1[3], cw2[3];
    #pragma unroll
    for (int jj = 0; jj < 3; ++jj) {
        int ch = n0 + wn * 48 + jj * 16 + l16;
        bool v = ch < CH;
        cb1[jj] = v ? b1[ch] : 0.0f;
        cw2[jj] = v ? w2[ch] : 0.0f;
    }
    float* red = (float*)lds;   // [64][4]
    #pragma unroll
    for (int ii = 0; ii < 4; ++ii)
        #pragma unroll
        for (int r = 0; r < 4; ++r) {
            float P = 0.0f;
            #pragma unroll
            for (int jj = 0; jj < 3; ++jj) {
                float h = acc[ii][jj][r] + cb1[jj];
                if (h > 0.0f) P += h * cw2[jj];
            }
            P += __shfl_xor(P, 1);
            P += __shfl_xor(P, 2);
            P += __shfl_xor(P, 4);
            P += __shfl_xor(P, 8);
            if (l16 == 0)
                red[(ii * 16 + quad * 4 + r) * 4 + wn] = P;
        }
    __syncthreads();
    if (tid < 64) {
        int l = l0 + tid;
        if (l < LCONV)
            atomicAdd(&logits[b * LCONV + l],
                      red[tid * 4] + red[tid * 4 + 1] + red[tid * 4 + 2] + red[tid * 4 + 3]);
    }
}

// ---------------------------------------------------------------------------
// Exact fp32 fixup: any |logit| < 0.02 (>>50 sigma of fp16 GEMM error) gets
// recomputed exactly from hidden/w1 in fp32. Expected flagged: <1 position.
// ---------------------------------------------------------------------------
__global__ __launch_bounds__(256) void fixup_kernel(
        const float* __restrict__ hidden, const float* __restrict__ w1,
        const float* __restrict__ b1, const float* __restrict__ w2,
        const float* __restrict__ b2, float* __restrict__ logits) {
    const int b = blockIdx.y, l0 = blockIdx.x * 64, tid = threadIdx.x;
    __shared__ float hrow[3 * 1024];
    __shared__ float sred[256];
    __shared__ int flags[64];
    __shared__ int nflag;
    if (tid == 0) nflag = 0;
    __syncthreads();
    if (tid < 64) {
        int l = l0 + tid;
        if (l < LCONV) {
            float v = logits[b * LCONV + l];
            if (fabsf(v) < 0.02f) { int k = atomicAdd(&nflag, 1); flags[k] = l; }
        }
    }
    __syncthreads();
    const int nf = nflag;
    for (int fi = 0; fi < nf; ++fi) {
        const int l = flags[fi];
        // rows l..l+2 of hidden are 3072 contiguous floats
        for (int t = tid; t < 3072; t += 256)
            hrow[t] = hidden[((size_t)b * L_SZ + l) * 1024 + t];
        __syncthreads();
        float tot = 0.0f;
        for (int c = tid; c < CH; c += 256) {
            const float* wr = w1 + (size_t)c * 3072;
            float dot = 0.0f;
            for (int d = 0; d < 1024; ++d)
                dot += hrow[d] * wr[d * 3] + hrow[1024 + d] * wr[d * 3 + 1]
                     + hrow[2048 + d] * wr[d * 3 + 2];
            float h = dot + b1[c];
            if (h > 0.0f) tot += h * w2[c];
        }
        sred[tid] = tot; __syncthreads();
        for (int off = 128; off > 0; off >>= 1) {
            if (tid < off) sred[tid] += sred[tid + off];
            __syncthreads();
        }
        if (tid == 0) logits[b * LCONV + l] = sred[0] + b2[0];
        __syncthreads();
    }
}

// ---------------------------------------------------------------------------
// Boundary scan: hard bits, segment starts, short_mask, scalar outputs.
// (segid dropped — pooling now walks contiguous segstart ranges directly.)
// ---------------------------------------------------------------------------
__global__ void boundary_scan_kernel(const float* __restrict__ logits,
                                     const float* __restrict__ amask,
                                     int* __restrict__ segstart,
                                     float* __restrict__ out_nb,
                                     float* __restrict__ out_tp,
                                     float* __restrict__ short_mask) {
    const int b = blockIdx.x, tid = threadIdx.x;
    __shared__ int sdata[256];
    __shared__ int s_len, s_total;

    int cnt = 0;
    #pragma unroll
    for (int j = 0; j < 8; ++j) {
        int l = tid * 8 + j;
        cnt += (amask[b * L_SZ + l] > 0.5f) ? 1 : 0;
    }
    sdata[tid] = cnt; __syncthreads();
    for (int off = 128; off > 0; off >>= 1) {
        if (tid < off) sdata[tid] += sdata[tid + off];
        __syncthreads();
    }
    if (tid == 0) s_len = sdata[0];
    __syncthreads();
    const int len = s_len;

    int bits[8]; int tsum = 0;
    #pragma unroll
    for (int j = 0; j < 8; ++j) {
        int l = tid * 8 + j;
        int h = 0;
        if (l >= 2 && l < len) h = (logits[b * LCONV + (l - 2)] > 0.0f) ? 1 : 0;
        if (len < L_SZ && l == len - 1) h = 1;
        bits[j] = h; tsum += h;
    }
    __syncthreads();
    sdata[tid] = tsum; __syncthreads();
    for (int off = 1; off < 256; off <<= 1) {
        int v = (tid >= off) ? sdata[tid - off] : 0;
        __syncthreads();
        sdata[tid] += v;
        __syncthreads();
    }
    const int texcl = sdata[tid] - tsum;
    if (tid == 255) s_total = sdata[255];
    __syncthreads();
    const int total = s_total;

    for (int s = tid; s <= NSEG; s += 256)
        segstart[b * (NSEG + 1) + s] = (s == 0) ? 0 : len;
    __syncthreads();
    int run = texcl;
    #pragma unroll
    for (int j = 0; j < 8; ++j) {
        int l = tid * 8 + j;
        if (bits[j]) {
            if (run + 1 <= NSEG) segstart[b * (NSEG + 1) + run + 1] = l + 1;
            run++;
        }
    }

    if (tid == 0) {
        atomicAdd(out_nb, (float)total);
        atomicAdd(out_tp, (float)len);
    }
    for (int s = tid; s < NSEG; s += 256)
        short_mask[b * NSEG + s] = (s < total) ? 1.0f : 0.0f;
}

// ---------------------------------------------------------------------------
// Fused pool: block (s,b) sums the contiguous token range
// [segstart[s], segstart[s+1]) of hidden (fp32, coalesced 4 KB/row),
// divides by count, adds sinusoidal PE, writes pooled once.
// Replaces pool_accum (2.4M atomics) + pool_final (32 MB extra traffic)
// + the 16 MB pooled memset. Empty segments: sum=0 -> 0*inv + PE.
// ---------------------------------------------------------------------------
__global__ __launch_bounds__(256) void pool_kernel(
        const float* __restrict__ hidden, const int* __restrict__ segstart,
        float* __restrict__ pooled) {
    const int s = blockIdx.x, b = blockIdx.y, tid = threadIdx.x;
    const int l0 = segstart[b * (NSEG + 1) + s];
    const int l1 = segstart[b * (NSEG + 1) + s + 1];
    const int d0 = tid * 4;
    const float* hb = hidden + (size_t)b * L_SZ * D_SZ + d0;
    float4 acc = make_float4(0.f, 0.f, 0.f, 0.f);
    for (int l = l0; l < l1; ++l) {
        float4 v = *(const float4*)(hb + (size_t)l * D_SZ);
        acc.x += v.x; acc.y += v.y; acc.z += v.z; acc.w += v.w;
    }
    const float inv = 1.0f / ((float)(l1 - l0) + 1e-9f);
    const float ce = -9.210340371976184f / 512.0f;
    const int i = d0 >> 1;
    const float a0 = (float)s * expf(ce * (float)i);
    const float a1 = (float)s * expf(ce * (float)(i + 1));
    float4 out;
    out.x = acc.x * inv + sinf(a0);
    out.y = acc.y * inv + cosf(a0);
    out.z = acc.z * inv + sinf(a1);
    out.w = acc.w * inv + cosf(a1);
    *(float4*)(pooled + ((size_t)(b * NSEG + s)) * D_SZ + d0) = out;
}

// ---------------------------------------------------------------------------
extern "C" void kernel_launch(void* const* d_in, const int* in_sizes, int n_in,
                              void* d_out, int out_size, void* d_ws, size_t ws_size,
                              hipStream_t stream) {
    const float* hidden = (const float*)d_in[0];
    const float* amask  = (const float*)d_in[1];
    const float* w1     = (const float*)d_in[2];
    const float* b1     = (const float*)d_in[3];
    const float* w2     = (const float*)d_in[4];
    const float* b2     = (const float*)d_in[5];

    float* out    = (float*)d_out;
    float* pooled = out;
    float* nb     = out + POOLED_N;
    float* tp     = nb + 1;
    float* smask  = out + POOLED_N + 2;

    // zero only the two scalar accumulators (pooled fully written by
    // pool_kernel; short_mask fully written by scan)
    hipMemsetAsync(nb, 0, 2 * sizeof(float), stream);

    const size_t HID_E = (size_t)B_SZ * L_SZ * D_SZ;           // 16,777,216
    const size_t OFF_HID16    = 0;
    const size_t OFF_BPACK    = OFF_HID16 + HID_E * 2;                 // 32 MB
    const size_t OFF_LOGITS   = OFF_BPACK + (size_t)CP * KDIM * 2;     // +2.25 MB
    const size_t OFF_SEGSTART = OFF_LOGITS + (size_t)B_SZ * LCONV * 4;

    _Float16* hid16  = (_Float16*)((char*)d_ws + OFF_HID16);
    _Float16* bfrag  = (_Float16*)((char*)d_ws + OFF_BPACK);
    float*    logits = (float*)((char*)d_ws + OFF_LOGITS);
    int*      segst  = (int*)((char*)d_ws + OFF_SEGSTART);

    convert_hidden_kernel<<<(int)(HID_E / 8 / 256), 256, 0, stream>>>(hidden, hid16);
    convert_w1_kernel<<<(CP * KDIM) / 256, 256, 0, stream>>>(w1, b2, bfrag, logits);
    conv_mfma_kernel<<<dim3(2, 32, B_SZ), 256, 0, stream>>>(hid16, bfrag, b1, w2, logits);
    fixup_kernel<<<dim3(32, B_SZ), 256, 0, stream>>>(hidden, w1, b1, w2, b2, logits);
    boundary_scan_kernel<<<B_SZ, 256, 0, stream>>>(logits, amask, segst, nb, tp, smask);
    pool_kernel<<<dim3(NSEG, B_SZ), 256, 0, stream>>>(hidden, segst, pooled);
}

// Round 7
// 239.906 us; speedup vs baseline: 3.0371x; 3.0371x over previous
//
#include <hip/hip_runtime.h>
#include <hip/hip_bf16.h>
#include <cmath>

// Problem constants
#define B_SZ 8
#define L_SZ 2048
#define D_SZ 1024
#define CH 341
#define CP 384               // padded channel dim (24 x 16)
#define LCONV 2046           // L - KERNEL + 1
#define NSEG 512
#define KDIM 3072            // 3 * 1024 folded conv K
#define KSTEPS 48            // KDIM / 64

#define POOLED_N (B_SZ * NSEG * D_SZ)

typedef _Float16 f16x8 __attribute__((ext_vector_type(8)));
typedef float f32x4 __attribute__((ext_vector_type(4)));

__device__ __forceinline__ void gl_lds16(const void* g, void* l) {
    __builtin_amdgcn_global_load_lds(
        (const __attribute__((address_space(1))) unsigned int*)g,
        (__attribute__((address_space(3))) unsigned int*)l, 16, 0, 0);
}

// ---------------------------------------------------------------------------
// Convert hidden fp32 -> fp16 (single copy; fixup kernel guarantees sign
// correctness of thresholded logits, so one fp16 pass suffices)
// ---------------------------------------------------------------------------
__global__ __launch_bounds__(256) void convert_hidden_kernel(
        const float* __restrict__ hidden, _Float16* __restrict__ hid16) {
    size_t idx = (size_t)blockIdx.x * 256 + threadIdx.x;   // 8 elems / thread
    float4 v0 = ((const float4*)hidden)[idx * 2];
    float4 v1 = ((const float4*)hidden)[idx * 2 + 1];
    f16x8 o;
    o[0] = (_Float16)v0.x; o[1] = (_Float16)v0.y;
    o[2] = (_Float16)v0.z; o[3] = (_Float16)v0.w;
    o[4] = (_Float16)v1.x; o[5] = (_Float16)v1.y;
    o[6] = (_Float16)v1.z; o[7] = (_Float16)v1.w;
    ((f16x8*)hid16)[idx] = o;
}

// ---------------------------------------------------------------------------
// Convert w1 (Ch,D,K) -> bfrag in EXACT MFMA B-fragment order:
//   flat f16 index fo = (((tt*48 + s)*2 + kc)*64 + lane)*8 + j
//   content: channel c = tt*16 + (lane&15)
//            k         = s*64 + kc*32 + ((lane>>4)<<3) + j   (k' = kk*1024+d)
// so a wave's per-step B fragment is one contiguous 1 KB global_load_dwordx4.
// c padded to 384 with zeros. Also init logits to b2.
// ---------------------------------------------------------------------------
__global__ __launch_bounds__(256) void convert_w1_kernel(
        const float* __restrict__ w1, const float* __restrict__ b2,
        _Float16* __restrict__ bfrag, float* __restrict__ logits) {
    int idx = blockIdx.x * 256 + threadIdx.x;   // < 384*3072
    int j = idx & 7;
    int lane = (idx >> 3) & 63;
    int kc = (idx >> 9) & 1;
    int rest = idx >> 10;
    int s = rest % KSTEPS;
    int tt = rest / KSTEPS;
    int c = tt * 16 + (lane & 15);
    int k = s * 64 + kc * 32 + ((lane >> 4) << 3) + j;
    int kk = k >> 10, d = k & 1023;
    float v = (c < CH) ? w1[((size_t)c * 1024 + d) * 3 + kk] : 0.0f;
    bfrag[idx] = (_Float16)v;
    if (idx < B_SZ * LCONV) logits[idx] = b2[0];
}

// ---------------------------------------------------------------------------
// fp16 MFMA conv GEMM, B-in-registers, 3-deep counted-vmcnt pipeline,
// WAVE-TILE M=128 for B-reuse (R6 lever; R6 bench was an infra failure,
// this is the unchanged resubmit).
// R2-R4 triangulated: conv is VMEM-intensity bound (341 B/MFMA). Doubling
// the wave's M-tile (acc[8][3], 48 MFMA/step/wave) halves B bytes/MFMA
// (590 -> 295 MB total B traffic, 208 B/MFMA).
// Tile 128 l x 192 c, BK=64, 4 waves (1x4 over N strips of 48).
// Per step/thread: 6 B reg loads + 4 A gl_lds = 10 VMEM. 3-deep pipeline,
// s_waitcnt vmcnt(10) retires exactly the oldest batch; raw s_barrier.
// A triple-buffered in LDS (3 x 16 KB). Grid (2,16,8) = 256 blocks = 1/CU
// (occupancy will read ~12% — the test: perf up despite occupancy down
// confirms intensity-bound, not latency/occupancy-bound).
// Fused epilogue: relu(h+b1)*w2 reduced over c, atomicAdd into logits.
// ---------------------------------------------------------------------------
#define LDS_BUF 16384        // one A buffer (128 rows x 64 k x 2B)

#define WAITV10() asm volatile("s_waitcnt vmcnt(10)" ::: "memory")
#define WAITV0()  asm volatile("s_waitcnt vmcnt(0)" ::: "memory")
#define BAR()     __builtin_amdgcn_s_barrier()

#define LOAD_B(DST) do {                                                    \
    _Pragma("unroll")                                                       \
    for (int jj = 0; jj < 3; ++jj) {                                        \
        DST[jj][0] = bptr[jj][0];                                           \
        DST[jj][1] = bptr[jj][64];                                          \
        bptr[jj] += 128;                                                    \
    } } while (0)

#define ISSUE_A(OFF) do {                                                   \
    _Pragma("unroll")                                                       \
    for (int p = 0; p < 4; ++p) {                                           \
        gl_lds16(pa[p], lds + (OFF) + (p * 256 + wave * 64) * 16);          \
        pa[p] += 64;                                                        \
    } } while (0)

#define COMPUTE(OFF, BSET) do {                                             \
    _Pragma("unroll")                                                       \
    for (int kc = 0; kc < 2; ++kc) {                                        \
        f16x8 a[8];                                                         \
        _Pragma("unroll")                                                   \
        for (int ii = 0; ii < 8; ++ii)                                      \
            a[ii] = *(const f16x8*)(lds + (OFF) + (kc * 512 + ii * 64 + lane) * 16); \
        _Pragma("unroll")                                                   \
        for (int ii = 0; ii < 8; ++ii)                                      \
            _Pragma("unroll")                                               \
            for (int jj = 0; jj < 3; ++jj)                                  \
                acc[ii][jj] = __builtin_amdgcn_mfma_f32_16x16x32_f16(       \
                    a[ii], BSET[jj][kc], acc[ii][jj], 0, 0, 0);             \
    } } while (0)

__global__ __launch_bounds__(256) void conv_mfma_kernel(
        const _Float16* __restrict__ hid16, const _Float16* __restrict__ bfrag,
        const float* __restrict__ b1, const float* __restrict__ w2,
        float* __restrict__ logits) {
    const int nt = blockIdx.x;           // 0..1
    const int mt = blockIdx.y;           // 0..15
    const int b  = blockIdx.z;
    const int l0 = mt * 128;
    const int n0 = nt * 192;
    const int tid = threadIdx.x;
    const int wave = tid >> 6, lane = tid & 63;
    const int wn = wave;                 // 1x4 wave grid: wave = channel strip
    const int quad = lane >> 4, l16 = lane & 15;

    __shared__ __align__(16) char lds[3 * LDS_BUF];   // 48 KB: 3 x A 16K

    const _Float16* hb = hid16 + (size_t)b * L_SZ * D_SZ;

    // A staging source pointers: 1024 entries (2 kc x 512), 4 per thread.
    // entry e (within kc): i=e>>6 (row block 0..7), m=i*16+(e&15),
    // koff=((e>>4)&3)*8
    const _Float16* pa[4];
    #pragma unroll
    for (int p = 0; p < 4; ++p) {
        int f = p * 256 + tid;
        int kc = f >> 9, e = f & 511;
        int m = ((e >> 6) << 4) + (e & 15);
        int koff = ((e >> 4) & 3) * 8;
        int l = l0 + m; if (l > LCONV - 1) l = LCONV - 1;
        pa[p] = hb + (size_t)l * 1024 + kc * 32 + koff;
    }

    // B fragment pointers: one per jj, advancing 128 f16x8-units (2 KB) / step.
    const f16x8* bp = (const f16x8*)bfrag;
    const f16x8* bptr[3];
    #pragma unroll
    for (int jj = 0; jj < 3; ++jj) {
        int tt = nt * 12 + wn * 3 + jj;
        bptr[jj] = bp + (size_t)tt * (KSTEPS * 2 * 64) + lane;
    }

    f32x4 acc[8][3] = {};
    f16x8 B0[3][2], B1[3][2], B2[3][2];

    // ---- prologue: batches 0 and 1 in flight (10 VMEM each) ----
    LOAD_B(B0); ISSUE_A(0);
    LOAD_B(B1); ISSUE_A(LDS_BUF);

    // steps 0..44, unrolled by 3 (buffer/set rotation is compile-time)
    for (int t = 0; t < 15; ++t) {
        WAITV10(); BAR();                // batch 3t retired; 3t+1 in flight
        LOAD_B(B2); ISSUE_A(2 * LDS_BUF);  // issue batch 3t+2
        COMPUTE(0, B0);                  // compute step 3t

        WAITV10(); BAR();                // batch 3t+1 retired
        LOAD_B(B0); ISSUE_A(0);          // issue batch 3t+3
        COMPUTE(LDS_BUF, B1);            // compute step 3t+1

        WAITV10(); BAR();                // batch 3t+2 retired
        LOAD_B(B1); ISSUE_A(LDS_BUF);    // issue batch 3t+4
        COMPUTE(2 * LDS_BUF, B2);        // compute step 3t+2
    }
    // tail: steps 45,46,47 (batches 45,46 in flight; 47 not yet issued)
    WAITV10(); BAR();                    // batch 45 retired
    LOAD_B(B2); ISSUE_A(2 * LDS_BUF);    // issue batch 47
    COMPUTE(0, B0);                      // step 45
    WAITV10(); BAR();                    // batch 46 retired
    COMPUTE(LDS_BUF, B1);                // step 46
    WAITV0(); BAR();                     // batch 47 retired
    COMPUTE(2 * LDS_BUF, B2);            // step 47

    __syncthreads();          // before reusing lds as reduction scratch

    // --- epilogue: relu(acc + b1)*w2, reduce over c, atomic into logits ---
    float cb1[3], cw2[3];
    #pragma unroll
    for (int jj = 0; jj < 3; ++jj) {
        int ch = n0 + wn * 48 + jj * 16 + l16;
        bool v = ch < CH;
        cb1[jj] = v ? b1[ch] : 0.0f;
        cw2[jj] = v ? w2[ch] : 0.0f;
    }
    float* red = (float*)lds;   // [128][4]
    #pragma unroll
    for (int ii = 0; ii < 8; ++ii)
        #pragma unroll
        for (int r = 0; r < 4; ++r) {
            float P = 0.0f;
            #pragma unroll
            for (int jj = 0; jj < 3; ++jj) {
                float h = acc[ii][jj][r] + cb1[jj];
                if (h > 0.0f) P += h * cw2[jj];
            }
            P += __shfl_xor(P, 1);
            P += __shfl_xor(P, 2);
            P += __shfl_xor(P, 4);
            P += __shfl_xor(P, 8);
            if (l16 == 0)
                red[(ii * 16 + quad * 4 + r) * 4 + wn] = P;
        }
    __syncthreads();
    if (tid < 128) {
        int l = l0 + tid;
        if (l < LCONV)
            atomicAdd(&logits[b * LCONV + l],
                      red[tid * 4] + red[tid * 4 + 1] + red[tid * 4 + 2] + red[tid * 4 + 3]);
    }
}

// ---------------------------------------------------------------------------
// Exact fp32 fixup: any |logit| < 0.02 (>>50 sigma of fp16 GEMM error) gets
// recomputed exactly from hidden/w1 in fp32. Expected flagged: <1 position.
// ---------------------------------------------------------------------------
__global__ __launch_bounds__(256) void fixup_kernel(
        const float* __restrict__ hidden, const float* __restrict__ w1,
        const float* __restrict__ b1, const float* __restrict__ w2,
        const float* __restrict__ b2, float* __restrict__ logits) {
    const int b = blockIdx.y, l0 = blockIdx.x * 64, tid = threadIdx.x;
    __shared__ float hrow[3 * 1024];
    __shared__ float sred[256];
    __shared__ int flags[64];
    __shared__ int nflag;
    if (tid == 0) nflag = 0;
    __syncthreads();
    if (tid < 64) {
        int l = l0 + tid;
        if (l < LCONV) {
            float v = logits[b * LCONV + l];
            if (fabsf(v) < 0.02f) { int k = atomicAdd(&nflag, 1); flags[k] = l; }
        }
    }
    __syncthreads();
    const int nf = nflag;
    for (int fi = 0; fi < nf; ++fi) {
        const int l = flags[fi];
        // rows l..l+2 of hidden are 3072 contiguous floats
        for (int t = tid; t < 3072; t += 256)
            hrow[t] = hidden[((size_t)b * L_SZ + l) * 1024 + t];
        __syncthreads();
        float tot = 0.0f;
        for (int c = tid; c < CH; c += 256) {
            const float* wr = w1 + (size_t)c * 3072;
            float dot = 0.0f;
            for (int d = 0; d < 1024; ++d)
                dot += hrow[d] * wr[d * 3] + hrow[1024 + d] * wr[d * 3 + 1]
                     + hrow[2048 + d] * wr[d * 3 + 2];
            float h = dot + b1[c];
            if (h > 0.0f) tot += h * w2[c];
        }
        sred[tid] = tot; __syncthreads();
        for (int off = 128; off > 0; off >>= 1) {
            if (tid < off) sred[tid] += sred[tid + off];
            __syncthreads();
        }
        if (tid == 0) logits[b * LCONV + l] = sred[0] + b2[0];
        __syncthreads();
    }
}

// ---------------------------------------------------------------------------
// Boundary scan: hard bits, segment starts, per-token segment ids,
// short_mask, scalar outputs.  (segid needed by token-parallel pool_accum —
// R5 showed per-segment pooling serializes on the few, very long segments.)
// ---------------------------------------------------------------------------
__global__ void boundary_scan_kernel(const float* __restrict__ logits,
                                     const float* __restrict__ amask,
                                     int* __restrict__ segstart,
                                     int* __restrict__ segid,
                                     float* __restrict__ out_nb,
                                     float* __restrict__ out_tp,
                                     float* __restrict__ short_mask) {
    const int b = blockIdx.x, tid = threadIdx.x;
    __shared__ int sdata[256];
    __shared__ int s_len, s_total;

    int cnt = 0;
    #pragma unroll
    for (int j = 0; j < 8; ++j) {
        int l = tid * 8 + j;
        cnt += (amask[b * L_SZ + l] > 0.5f) ? 1 : 0;
    }
    sdata[tid] = cnt; __syncthreads();
    for (int off = 128; off > 0; off >>= 1) {
        if (tid < off) sdata[tid] += sdata[tid + off];
        __syncthreads();
    }
    if (tid == 0) s_len = sdata[0];
    __syncthreads();
    const int len = s_len;

    int bits[8]; int tsum = 0;
    #pragma unroll
    for (int j = 0; j < 8; ++j) {
        int l = tid * 8 + j;
        int h = 0;
        if (l >= 2 && l < len) h = (logits[b * LCONV + (l - 2)] > 0.0f) ? 1 : 0;
        if (len < L_SZ && l == len - 1) h = 1;
        bits[j] = h; tsum += h;
    }
    __syncthreads();
    sdata[tid] = tsum; __syncthreads();
    for (int off = 1; off < 256; off <<= 1) {
        int v = (tid >= off) ? sdata[tid - off] : 0;
        __syncthreads();
        sdata[tid] += v;
        __syncthreads();
    }
    const int texcl = sdata[tid] - tsum;
    if (tid == 255) s_total = sdata[255];
    __syncthreads();
    const int total = s_total;

    for (int s = tid; s <= NSEG; s += 256)
        segstart[b * (NSEG + 1) + s] = (s == 0) ? 0 : len;
    __syncthreads();
    int run = texcl;
    #pragma unroll
    for (int j = 0; j < 8; ++j) {
        int l = tid * 8 + j;
        int sv = -1;
        if (l < len && run < NSEG) sv = run;
        segid[b * L_SZ + l] = sv;
        if (bits[j]) {
            if (run + 1 <= NSEG) segstart[b * (NSEG + 1) + run + 1] = l + 1;
            run++;
        }
    }

    if (tid == 0) {
        atomicAdd(out_nb, (float)total);
        atomicAdd(out_tp, (float)len);
    }
    for (int s = tid; s < NSEG; s += 256)
        short_mask[b * NSEG + s] = (s < total) ? 1.0f : 0.0f;
}

// ---------------------------------------------------------------------------
// Pool accumulate: 16-token chunks, thread = 4 d over the chunk, atomic flush
// per segment run. Grid (128,8) = 1024 blocks x 256 threads.
// (Parallel across TOKENS — segments are few and very long, so per-segment
// blocks serialize; this decomposition is the R4 known-good.)
// ---------------------------------------------------------------------------
__global__ __launch_bounds__(256) void pool_accum_kernel(
        const float* __restrict__ hidden, const int* __restrict__ segid,
        float* __restrict__ pooled) {
    const int chunk = blockIdx.x, b = blockIdx.y;
    const int tid = threadIdx.x;
    const int d0 = tid * 4;
    const int lbase = chunk * 16;
    const float* hb = hidden + (size_t)b * L_SZ * D_SZ + d0;
    const int* sg = segid + b * L_SZ + lbase;
    float4 acc = make_float4(0.f, 0.f, 0.f, 0.f);
    int cur = -1;
    #pragma unroll
    for (int t = 0; t < 16; ++t) {
        int sid = sg[t];
        if (sid != cur) {
            if (cur >= 0) {
                float* dst = pooled + ((size_t)(b * NSEG + cur)) * D_SZ + d0;
                atomicAdd(dst + 0, acc.x); atomicAdd(dst + 1, acc.y);
                atomicAdd(dst + 2, acc.z); atomicAdd(dst + 3, acc.w);
            }
            acc = make_float4(0.f, 0.f, 0.f, 0.f);
            cur = sid;
        }
        if (sid >= 0) {
            float4 v = *(const float4*)(hb + (size_t)(lbase + t) * D_SZ);
            acc.x += v.x; acc.y += v.y; acc.z += v.z; acc.w += v.w;
        }
    }
    if (cur >= 0) {
        float* dst = pooled + ((size_t)(b * NSEG + cur)) * D_SZ + d0;
        atomicAdd(dst + 0, acc.x); atomicAdd(dst + 1, acc.y);
        atomicAdd(dst + 2, acc.z); atomicAdd(dst + 3, acc.w);
    }
}

// ---------------------------------------------------------------------------
// Pool finalize: divide by count, add sinusoidal PE.
// ---------------------------------------------------------------------------
__global__ __launch_bounds__(256) void pool_final_kernel(
        float* __restrict__ pooled, const int* __restrict__ segstart) {
    const int s = blockIdx.x, b = blockIdx.y, tid = threadIdx.x;
    const int l0 = segstart[b * (NSEG + 1) + s];
    const int l1 = segstart[b * (NSEG + 1) + s + 1];
    const float inv = 1.0f / ((float)(l1 - l0) + 1e-9f);
    const int d0 = tid * 4;
    size_t o = ((size_t)(b * NSEG + s)) * D_SZ + d0;
    float4 v = *(float4*)(pooled + o);
    const float ce = -9.210340371976184f / 512.0f;
    const int i = d0 >> 1;
    const float a0 = (float)s * expf(ce * (float)i);
    const float a1 = (float)s * expf(ce * (float)(i + 1));
    float4 out;
    out.x = v.x * inv + sinf(a0);
    out.y = v.y * inv + cosf(a0);
    out.z = v.z * inv + sinf(a1);
    out.w = v.w * inv + cosf(a1);
    *(float4*)(pooled + o) = out;
}

// ---------------------------------------------------------------------------
extern "C" void kernel_launch(void* const* d_in, const int* in_sizes, int n_in,
                              void* d_out, int out_size, void* d_ws, size_t ws_size,
                              hipStream_t stream) {
    const float* hidden = (const float*)d_in[0];
    const float* amask  = (const float*)d_in[1];
    const float* w1     = (const float*)d_in[2];
    const float* b1     = (const float*)d_in[3];
    const float* w2     = (const float*)d_in[4];
    const float* b2     = (const float*)d_in[5];

    float* out    = (float*)d_out;
    float* pooled = out;
    float* nb     = out + POOLED_N;
    float* tp     = nb + 1;
    float* smask  = out + POOLED_N + 2;

    // zero pooled + scalars (short_mask fully overwritten by scan)
    hipMemsetAsync(d_out, 0, (size_t)(POOLED_N + 2) * sizeof(float), stream);

    const size_t HID_E = (size_t)B_SZ * L_SZ * D_SZ;           // 16,777,216
    const size_t OFF_HID16    = 0;
    const size_t OFF_BPACK    = OFF_HID16 + HID_E * 2;                 // 32 MB
    const size_t OFF_LOGITS   = OFF_BPACK + (size_t)CP * KDIM * 2;     // +2.25 MB
    const size_t OFF_SEGSTART = OFF_LOGITS + (size_t)B_SZ * LCONV * 4;
    const size_t OFF_SEGID    = OFF_SEGSTART + (size_t)B_SZ * (NSEG + 1) * 4;

    _Float16* hid16  = (_Float16*)((char*)d_ws + OFF_HID16);
    _Float16* bfrag  = (_Float16*)((char*)d_ws + OFF_BPACK);
    float*    logits = (float*)((char*)d_ws + OFF_LOGITS);
    int*      segst  = (int*)((char*)d_ws + OFF_SEGSTART);
    int*      segid  = (int*)((char*)d_ws + OFF_SEGID);

    convert_hidden_kernel<<<(int)(HID_E / 8 / 256), 256, 0, stream>>>(hidden, hid16);
    convert_w1_kernel<<<(CP * KDIM) / 256, 256, 0, stream>>>(w1, b2, bfrag, logits);
    conv_mfma_kernel<<<dim3(2, 16, B_SZ), 256, 0, stream>>>(hid16, bfrag, b1, w2, logits);
    fixup_kernel<<<dim3(32, B_SZ), 256, 0, stream>>>(hidden, w1, b1, w2, b2, logits);
    boundary_scan_kernel<<<B_SZ, 256, 0, stream>>>(logits, amask, segst, segid, nb, tp, smask);
    pool_accum_kernel<<<dim3(128, B_SZ), 256, 0, stream>>>(hidden, segid, pooled);
    pool_final_kernel<<<dim3(NSEG, B_SZ), 256, 0, stream>>>(pooled, segst);
}

// Round 8
// 207.964 us; speedup vs baseline: 3.5036x; 1.1536x over previous
//
#include <hip/hip_runtime.h>
#include <hip/hip_bf16.h>
#include <cmath>

// Problem constants
#define B_SZ 8
#define L_SZ 2048
#define D_SZ 1024
#define CH 341
#define CP 384               // padded channel dim (24 x 16)
#define LCONV 2046           // L - KERNEL + 1
#define NSEG 512
#define KDIM 3072            // 3 * 1024 folded conv K
#define KSTEPS 48            // KDIM / 64
#define NCHUNK 128           // 16-token pooling chunks per batch
#define NSLOT 640            // run-slot bound: NCHUNK + NSEG - 1, padded

#define POOLED_N (B_SZ * NSEG * D_SZ)

typedef _Float16 f16x8 __attribute__((ext_vector_type(8)));
typedef float f32x4 __attribute__((ext_vector_type(4)));

__device__ __forceinline__ void gl_lds16(const void* g, void* l) {
    __builtin_amdgcn_global_load_lds(
        (const __attribute__((address_space(1))) unsigned int*)g,
        (__attribute__((address_space(3))) unsigned int*)l, 16, 0, 0);
}

// ---------------------------------------------------------------------------
// Convert hidden fp32 -> fp16 (single copy; fixup kernel guarantees sign
// correctness of thresholded logits, so one fp16 pass suffices)
// ---------------------------------------------------------------------------
__global__ __launch_bounds__(256) void convert_hidden_kernel(
        const float* __restrict__ hidden, _Float16* __restrict__ hid16) {
    size_t idx = (size_t)blockIdx.x * 256 + threadIdx.x;   // 8 elems / thread
    float4 v0 = ((const float4*)hidden)[idx * 2];
    float4 v1 = ((const float4*)hidden)[idx * 2 + 1];
    f16x8 o;
    o[0] = (_Float16)v0.x; o[1] = (_Float16)v0.y;
    o[2] = (_Float16)v0.z; o[3] = (_Float16)v0.w;
    o[4] = (_Float16)v1.x; o[5] = (_Float16)v1.y;
    o[6] = (_Float16)v1.z; o[7] = (_Float16)v1.w;
    ((f16x8*)hid16)[idx] = o;
}

// ---------------------------------------------------------------------------
// Convert w1 (Ch,D,K) -> bfrag in EXACT MFMA B-fragment order:
//   flat f16 index fo = (((tt*48 + s)*2 + kc)*64 + lane)*8 + j
//   content: channel c = tt*16 + (lane&15)
//            k         = s*64 + kc*32 + ((lane>>4)<<3) + j   (k' = kk*1024+d)
// so a wave's per-step B fragment is one contiguous 1 KB global_load_dwordx4.
// c padded to 384 with zeros. Also init logits to b2.
// ---------------------------------------------------------------------------
__global__ __launch_bounds__(256) void convert_w1_kernel(
        const float* __restrict__ w1, const float* __restrict__ b2,
        _Float16* __restrict__ bfrag, float* __restrict__ logits) {
    int idx = blockIdx.x * 256 + threadIdx.x;   // < 384*3072
    int j = idx & 7;
    int lane = (idx >> 3) & 63;
    int kc = (idx >> 9) & 1;
    int rest = idx >> 10;
    int s = rest % KSTEPS;
    int tt = rest / KSTEPS;
    int c = tt * 16 + (lane & 15);
    int k = s * 64 + kc * 32 + ((lane >> 4) << 3) + j;
    int kk = k >> 10, d = k & 1023;
    float v = (c < CH) ? w1[((size_t)c * 1024 + d) * 3 + kk] : 0.0f;
    bfrag[idx] = (_Float16)v;
    if (idx < B_SZ * LCONV) logits[idx] = b2[0];
}

// ---------------------------------------------------------------------------
// fp16 MFMA conv GEMM, B-in-registers (R2 configuration — measured best at
// 57.8 us across R2/R3/R4/R7; conv is frozen at this empirical optimum).
// Tile 64 l x 192 c, BK=64, 4 waves (1x4), wave-tile 64x48 (4x3 of 16x16x32)
// -> 24 MFMAs per step per wave. B loaded per step straight into registers
// from fragment-ordered bfrag, prefetched one step ahead; A double-buffered
// in LDS via gl_lds16 (16 KB). Grid (2,32,8) = 512 blocks = 2/CU.
// Fused epilogue: relu(h+b1)*w2 reduced over c, atomicAdd into logits.
// ---------------------------------------------------------------------------
#define LDS_BUF 8192         // byte offset between the two A buffers

__global__ __launch_bounds__(256, 2) void conv_mfma_kernel(
        const _Float16* __restrict__ hid16, const _Float16* __restrict__ bfrag,
        const float* __restrict__ b1, const float* __restrict__ w2,
        float* __restrict__ logits) {
    const int nt = blockIdx.x;           // 0..1
    const int mt = blockIdx.y;           // 0..31
    const int b  = blockIdx.z;
    const int l0 = mt * 64;
    const int n0 = nt * 192;
    const int tid = threadIdx.x;
    const int wave = tid >> 6, lane = tid & 63;
    const int wn = wave;                 // 1x4 wave grid: wave = channel strip
    const int quad = lane >> 4, l16 = lane & 15;

    __shared__ __align__(16) char lds[2 * LDS_BUF];   // 16 KB: 2 x A 8K

    const _Float16* hb = hid16 + (size_t)b * L_SZ * D_SZ;

    // A staging source pointers: 512 entries (2 kc x 256), 2 per thread.
    // entry e (within kc): i=e>>6 (row block), m=i*16+(e&15), koff=((e>>4)&3)*8
    const _Float16* pa[2];
    #pragma unroll
    for (int p = 0; p < 2; ++p) {
        int f = p * 256 + tid;
        int kc = f >> 8, e = f & 255;
        int m = ((e >> 6) << 4) + (e & 15);
        int koff = ((e >> 4) & 3) * 8;
        int l = l0 + m; if (l > LCONV - 1) l = LCONV - 1;
        pa[p] = hb + (size_t)l * 1024 + kc * 32 + koff;
    }

    // B fragment pointers: one per jj, advancing 128 f16x8-units (2 KB) / step.
    // Fragment (tt, s, kc) lives at f16x8-unit index ((tt*48+s)*2+kc)*64 + lane.
    const f16x8* bp = (const f16x8*)bfrag;
    const f16x8* bptr[3];
    #pragma unroll
    for (int jj = 0; jj < 3; ++jj) {
        int tt = nt * 12 + wn * 3 + jj;
        bptr[jj] = bp + (size_t)tt * (KSTEPS * 2 * 64) + lane;
    }

    f32x4 acc[4][3] = {};
    f16x8 bc[3][2], bn[3][2];

    // ---- prologue: B step 0 into regs, A step 0 into buffer 0 ----
    #pragma unroll
    for (int jj = 0; jj < 3; ++jj)
        #pragma unroll
        for (int kc = 0; kc < 2; ++kc)
            bc[jj][kc] = bptr[jj][kc * 64];
    #pragma unroll
    for (int jj = 0; jj < 3; ++jj) bptr[jj] += 128;
    #pragma unroll
    for (int p = 0; p < 2; ++p)
        gl_lds16(pa[p], lds + (p * 256 + wave * 64) * 16);
    #pragma unroll
    for (int p = 0; p < 2; ++p) pa[p] += 64;
    __syncthreads();          // buffer 0 + bc ready

    int cur = 0;
    for (int s = 0; s < KSTEPS - 1; ++s) {
        const int nxt = cur ^ LDS_BUF;
        // prefetch B step s+1 into regs (consumed next iter; completes by barrier)
        #pragma unroll
        for (int jj = 0; jj < 3; ++jj)
            #pragma unroll
            for (int kc = 0; kc < 2; ++kc)
                bn[jj][kc] = bptr[jj][kc * 64];
        #pragma unroll
        for (int jj = 0; jj < 3; ++jj) bptr[jj] += 128;
        // prefetch A step s+1 into other LDS buffer
        #pragma unroll
        for (int p = 0; p < 2; ++p)
            gl_lds16(pa[p], lds + nxt + (p * 256 + wave * 64) * 16);
        #pragma unroll
        for (int p = 0; p < 2; ++p) pa[p] += 64;

        // compute step s from cur + bc
        #pragma unroll
        for (int kc = 0; kc < 2; ++kc) {
            f16x8 a[4];
            #pragma unroll
            for (int ii = 0; ii < 4; ++ii)
                a[ii] = *(const f16x8*)(lds + cur + (kc * 256 + ii * 64 + lane) * 16);
            #pragma unroll
            for (int ii = 0; ii < 4; ++ii)
                #pragma unroll
                for (int jj = 0; jj < 3; ++jj)
                    acc[ii][jj] = __builtin_amdgcn_mfma_f32_16x16x32_f16(
                        a[ii], bc[jj][kc], acc[ii][jj], 0, 0, 0);
        }
        __syncthreads();      // vmcnt(0): A nxt + B s+1 landed; cur reads done
        #pragma unroll
        for (int jj = 0; jj < 3; ++jj)
            #pragma unroll
            for (int kc = 0; kc < 2; ++kc)
                bc[jj][kc] = bn[jj][kc];
        cur = nxt;
    }
    // final step (no prefetch)
    #pragma unroll
    for (int kc = 0; kc < 2; ++kc) {
        f16x8 a[4];
        #pragma unroll
        for (int ii = 0; ii < 4; ++ii)
            a[ii] = *(const f16x8*)(lds + cur + (kc * 256 + ii * 64 + lane) * 16);
        #pragma unroll
        for (int ii = 0; ii < 4; ++ii)
            #pragma unroll
            for (int jj = 0; jj < 3; ++jj)
                acc[ii][jj] = __builtin_amdgcn_mfma_f32_16x16x32_f16(
                    a[ii], bc[jj][kc], acc[ii][jj], 0, 0, 0);
    }
    __syncthreads();          // before reusing lds as reduction scratch

    // --- epilogue: relu(acc + b1)*w2, reduce over c, atomic into logits ---
    float cb1[3], cw2[3];
    #pragma unroll
    for (int jj = 0; jj < 3; ++jj) {
        int ch = n0 + wn * 48 + jj * 16 + l16;
        bool v = ch < CH;
        cb1[jj] = v ? b1[ch] : 0.0f;
        cw2[jj] = v ? w2[ch] : 0.0f;
    }
    float* red = (float*)lds;   // [64][4]
    #pragma unroll
    for (int ii = 0; ii < 4; ++ii)
        #pragma unroll
        for (int r = 0; r < 4; ++r) {
            float P = 0.0f;
            #pragma unroll
            for (int jj = 0; jj < 3; ++jj) {
                float h = acc[ii][jj][r] + cb1[jj];
                if (h > 0.0f) P += h * cw2[jj];
            }
            P += __shfl_xor(P, 1);
            P += __shfl_xor(P, 2);
            P += __shfl_xor(P, 4);
            P += __shfl_xor(P, 8);
            if (l16 == 0)
                red[(ii * 16 + quad * 4 + r) * 4 + wn] = P;
        }
    __syncthreads();
    if (tid < 64) {
        int l = l0 + tid;
        if (l < LCONV)
            atomicAdd(&logits[b * LCONV + l],
                      red[tid * 4] + red[tid * 4 + 1] + red[tid * 4 + 2] + red[tid * 4 + 3]);
    }
}

// ---------------------------------------------------------------------------
// Exact fp32 fixup: any |logit| < 0.02 (>>50 sigma of fp16 GEMM error) gets
// recomputed exactly from hidden/w1 in fp32. Expected flagged: <1 position.
// ---------------------------------------------------------------------------
__global__ __launch_bounds__(256) void fixup_kernel(
        const float* __restrict__ hidden, const float* __restrict__ w1,
        const float* __restrict__ b1, const float* __restrict__ w2,
        const float* __restrict__ b2, float* __restrict__ logits) {
    const int b = blockIdx.y, l0 = blockIdx.x * 64, tid = threadIdx.x;
    __shared__ float hrow[3 * 1024];
    __shared__ float sred[256];
    __shared__ int flags[64];
    __shared__ int nflag;
    if (tid == 0) nflag = 0;
    __syncthreads();
    if (tid < 64) {
        int l = l0 + tid;
        if (l < LCONV) {
            float v = logits[b * LCONV + l];
            if (fabsf(v) < 0.02f) { int k = atomicAdd(&nflag, 1); flags[k] = l; }
        }
    }
    __syncthreads();
    const int nf = nflag;
    for (int fi = 0; fi < nf; ++fi) {
        const int l = flags[fi];
        // rows l..l+2 of hidden are 3072 contiguous floats
        for (int t = tid; t < 3072; t += 256)
            hrow[t] = hidden[((size_t)b * L_SZ + l) * 1024 + t];
        __syncthreads();
        float tot = 0.0f;
        for (int c = tid; c < CH; c += 256) {
            const float* wr = w1 + (size_t)c * 3072;
            float dot = 0.0f;
            for (int d = 0; d < 1024; ++d)
                dot += hrow[d] * wr[d * 3] + hrow[1024 + d] * wr[d * 3 + 1]
                     + hrow[2048 + d] * wr[d * 3 + 2];
            float h = dot + b1[c];
            if (h > 0.0f) tot += h * w2[c];
        }
        sred[tid] = tot; __syncthreads();
        for (int off = 128; off > 0; off >>= 1) {
            if (tid < off) sred[tid] += sred[tid + off];
            __syncthreads();
        }
        if (tid == 0) logits[b * LCONV + l] = sred[0] + b2[0];
        __syncthreads();
    }
}

// ---------------------------------------------------------------------------
// Boundary scan: hard bits, segment starts, per-token segment ids,
// short_mask, scalar outputs.
// ---------------------------------------------------------------------------
__global__ void boundary_scan_kernel(const float* __restrict__ logits,
                                     const float* __restrict__ amask,
                                     int* __restrict__ segstart,
                                     int* __restrict__ segid,
                                     float* __restrict__ out_nb,
                                     float* __restrict__ out_tp,
                                     float* __restrict__ short_mask) {
    const int b = blockIdx.x, tid = threadIdx.x;
    __shared__ int sdata[256];
    __shared__ int s_len, s_total;

    int cnt = 0;
    #pragma unroll
    for (int j = 0; j < 8; ++j) {
        int l = tid * 8 + j;
        cnt += (amask[b * L_SZ + l] > 0.5f) ? 1 : 0;
    }
    sdata[tid] = cnt; __syncthreads();
    for (int off = 128; off > 0; off >>= 1) {
        if (tid < off) sdata[tid] += sdata[tid + off];
        __syncthreads();
    }
    if (tid == 0) s_len = sdata[0];
    __syncthreads();
    const int len = s_len;

    int bits[8]; int tsum = 0;
    #pragma unroll
    for (int j = 0; j < 8; ++j) {
        int l = tid * 8 + j;
        int h = 0;
        if (l >= 2 && l < len) h = (logits[b * LCONV + (l - 2)] > 0.0f) ? 1 : 0;
        if (len < L_SZ && l == len - 1) h = 1;
        bits[j] = h; tsum += h;
    }
    __syncthreads();
    sdata[tid] = tsum; __syncthreads();
    for (int off = 1; off < 256; off <<= 1) {
        int v = (tid >= off) ? sdata[tid - off] : 0;
        __syncthreads();
        sdata[tid] += v;
        __syncthreads();
    }
    const int texcl = sdata[tid] - tsum;
    if (tid == 255) s_total = sdata[255];
    __syncthreads();
    const int total = s_total;

    for (int s = tid; s <= NSEG; s += 256)
        segstart[b * (NSEG + 1) + s] = (s == 0) ? 0 : len;
    __syncthreads();
    int run = texcl;
    #pragma unroll
    for (int j = 0; j < 8; ++j) {
        int l = tid * 8 + j;
        int sv = -1;
        if (l < len && run < NSEG) sv = run;
        segid[b * L_SZ + l] = sv;
        if (bits[j]) {
            if (run + 1 <= NSEG) segstart[b * (NSEG + 1) + run + 1] = l + 1;
            run++;
        }
    }

    if (tid == 0) {
        atomicAdd(out_nb, (float)total);
        atomicAdd(out_tp, (float)len);
    }
    for (int s = tid; s < NSEG; s += 256)
        short_mask[b * NSEG + s] = (s < total) ? 1.0f : 0.0f;
}

// ---------------------------------------------------------------------------
// Pool phase 1: contention-free chunk partials via the monotone-segid slot
// trick. Run r of chunk c with segment id s stores at slot (c + s):
// injective across all (chunk, run) pairs because segid is non-decreasing
// (slot_first(c+1) = c+1+sid_first(c+1) > c+sid_last(c) = slot_last(c)),
// and segment s's contributions occupy CONTIGUOUS slots [c0+s, c1+s].
// Plain float4 stores — replaces pool_accum's ~1M contended atomicAdds.
// Grid (128,8) x 256 thr (token-parallel, the R4-proven decomposition).
// ---------------------------------------------------------------------------
__global__ __launch_bounds__(256) void pool_partial_kernel(
        const float* __restrict__ hidden, const int* __restrict__ segid,
        float* __restrict__ runsum) {
    const int c = blockIdx.x, b = blockIdx.y;
    const int tid = threadIdx.x;
    const int d0 = tid * 4;
    const int lbase = c * 16;
    const float* hb = hidden + (size_t)b * L_SZ * D_SZ + d0;
    const int* sg = segid + b * L_SZ + lbase;
    float* rb = runsum + ((size_t)(b * NSLOT + c)) * D_SZ + d0;  // slot c+sid
    float4 acc = make_float4(0.f, 0.f, 0.f, 0.f);
    int cur = -1;
    #pragma unroll
    for (int t = 0; t < 16; ++t) {
        int sid = sg[t];
        if (sid != cur) {
            if (cur >= 0)
                *(float4*)(rb + (size_t)cur * D_SZ) = acc;
            acc = make_float4(0.f, 0.f, 0.f, 0.f);
            cur = sid;
        }
        if (sid >= 0) {
            float4 v = *(const float4*)(hb + (size_t)(lbase + t) * D_SZ);
            acc.x += v.x; acc.y += v.y; acc.z += v.z; acc.w += v.w;
        }
    }
    if (cur >= 0)
        *(float4*)(rb + (size_t)cur * D_SZ) = acc;
}

// ---------------------------------------------------------------------------
// Pool phase 2 (fused finalize): block (s,b) sums segment s's contiguous
// runsum slots [c0+s, c1+s] (<=128 coalesced 4 KB rows, L2/L3-hot), divides
// by count, adds sinusoidal PE, writes pooled once. Every element written
// -> no pooled memset. Empty segment: acc=0 -> 0*inv + PE (matches ref).
// ---------------------------------------------------------------------------
__global__ __launch_bounds__(256) void pool_gather_kernel(
        const float* __restrict__ runsum, const int* __restrict__ segstart,
        float* __restrict__ pooled) {
    const int s = blockIdx.x, b = blockIdx.y, tid = threadIdx.x;
    const int l0 = segstart[b * (NSEG + 1) + s];
    const int l1 = segstart[b * (NSEG + 1) + s + 1];
    const int d0 = tid * 4;
    float4 a0 = make_float4(0.f, 0.f, 0.f, 0.f);
    float4 a1 = make_float4(0.f, 0.f, 0.f, 0.f);
    if (l1 > l0) {
        const int c0 = l0 >> 4, c1 = (l1 - 1) >> 4;
        const float* rs = runsum + ((size_t)(b * NSLOT + s)) * D_SZ + d0;
        int c = c0;
        for (; c + 1 <= c1; c += 2) {
            float4 v0 = *(const float4*)(rs + (size_t)c * D_SZ);
            float4 v1 = *(const float4*)(rs + (size_t)(c + 1) * D_SZ);
            a0.x += v0.x; a0.y += v0.y; a0.z += v0.z; a0.w += v0.w;
            a1.x += v1.x; a1.y += v1.y; a1.z += v1.z; a1.w += v1.w;
        }
        if (c <= c1) {
            float4 v0 = *(const float4*)(rs + (size_t)c * D_SZ);
            a0.x += v0.x; a0.y += v0.y; a0.z += v0.z; a0.w += v0.w;
        }
    }
    const float inv = 1.0f / ((float)(l1 - l0) + 1e-9f);
    const float ce = -9.210340371976184f / 512.0f;
    const int i = d0 >> 1;
    const float t0 = (float)s * expf(ce * (float)i);
    const float t1 = (float)s * expf(ce * (float)(i + 1));
    float4 out;
    out.x = (a0.x + a1.x) * inv + sinf(t0);
    out.y = (a0.y + a1.y) * inv + cosf(t0);
    out.z = (a0.z + a1.z) * inv + sinf(t1);
    out.w = (a0.w + a1.w) * inv + cosf(t1);
    *(float4*)(pooled + ((size_t)(b * NSEG + s)) * D_SZ + d0) = out;
}

// ---------------------------------------------------------------------------
extern "C" void kernel_launch(void* const* d_in, const int* in_sizes, int n_in,
                              void* d_out, int out_size, void* d_ws, size_t ws_size,
                              hipStream_t stream) {
    const float* hidden = (const float*)d_in[0];
    const float* amask  = (const float*)d_in[1];
    const float* w1     = (const float*)d_in[2];
    const float* b1     = (const float*)d_in[3];
    const float* w2     = (const float*)d_in[4];
    const float* b2     = (const float*)d_in[5];

    float* out    = (float*)d_out;
    float* pooled = out;
    float* nb     = out + POOLED_N;
    float* tp     = nb + 1;
    float* smask  = out + POOLED_N + 2;

    // zero only the two scalar accumulators (pooled fully written by
    // pool_gather; short_mask fully written by scan)
    hipMemsetAsync(nb, 0, 2 * sizeof(float), stream);

    const size_t HID_E = (size_t)B_SZ * L_SZ * D_SZ;           // 16,777,216
    const size_t OFF_HID16    = 0;
    const size_t OFF_BPACK    = OFF_HID16 + HID_E * 2;                 // 32 MB
    const size_t OFF_LOGITS   = OFF_BPACK + (size_t)CP * KDIM * 2;     // +2.25 MB
    const size_t OFF_SEGSTART = OFF_LOGITS + (size_t)B_SZ * LCONV * 4;
    const size_t OFF_SEGID    = OFF_SEGSTART + (size_t)B_SZ * (NSEG + 1) * 4;

    _Float16* hid16  = (_Float16*)((char*)d_ws + OFF_HID16);
    _Float16* bfrag  = (_Float16*)((char*)d_ws + OFF_BPACK);
    float*    logits = (float*)((char*)d_ws + OFF_LOGITS);
    int*      segst  = (int*)((char*)d_ws + OFF_SEGSTART);
    int*      segid  = (int*)((char*)d_ws + OFF_SEGID);
    // runsum (8 x 640 x 1024 fp32 = 20 MB) OVERLAYS hid16 (32 MB): hid16 is
    // dead after conv_mfma; pool_partial runs strictly later on the stream.
    float*    runsum = (float*)((char*)d_ws + OFF_HID16);

    convert_hidden_kernel<<<(int)(HID_E / 8 / 256), 256, 0, stream>>>(hidden, hid16);
    convert_w1_kernel<<<(CP * KDIM) / 256, 256, 0, stream>>>(w1, b2, bfrag, logits);
    conv_mfma_kernel<<<dim3(2, 32, B_SZ), 256, 0, stream>>>(hid16, bfrag, b1, w2, logits);
    fixup_kernel<<<dim3(32, B_SZ), 256, 0, stream>>>(hidden, w1, b1, w2, b2, logits);
    boundary_scan_kernel<<<B_SZ, 256, 0, stream>>>(logits, amask, segst, segid, nb, tp, smask);
    pool_partial_kernel<<<dim3(NCHUNK, B_SZ), 256, 0, stream>>>(hidden, segid, runsum);
    pool_gather_kernel<<<dim3(NSEG, B_SZ), 256, 0, stream>>>(runsum, segst, pooled);
}

// Round 9
// 203.309 us; speedup vs baseline: 3.5838x; 1.0229x over previous
//
#include <hip/hip_runtime.h>
#include <hip/hip_bf16.h>
#include <cmath>

// Problem constants
#define B_SZ 8
#define L_SZ 2048
#define D_SZ 1024
#define CH 341
#define CP 384               // padded channel dim (24 x 16)
#define LCONV 2046           // L - KERNEL + 1
#define NSEG 512
#define KDIM 3072            // 3 * 1024 folded conv K
#define KSTEPS 48            // KDIM / 64
#define NCHUNK 128           // 16-token pooling chunks per batch
#define NSLOT 640            // run-slot bound: NCHUNK + NSEG - 1, padded

#define POOLED_N (B_SZ * NSEG * D_SZ)
#define HID_BLOCKS 8192      // 16,777,216 elems / 8 per thread / 256 threads
#define W1_BLOCKS 4608       // 384*3072 / 256

typedef _Float16 f16x8 __attribute__((ext_vector_type(8)));
typedef float f32x4 __attribute__((ext_vector_type(4)));

__device__ __forceinline__ void gl_lds16(const void* g, void* l) {
    __builtin_amdgcn_global_load_lds(
        (const __attribute__((address_space(1))) unsigned int*)g,
        (__attribute__((address_space(3))) unsigned int*)l, 16, 0, 0);
}

// ---------------------------------------------------------------------------
// Fused converts (1 dispatch instead of 2 — tail is launch-gap dominated):
// blocks [0, HID_BLOCKS): hidden fp32 -> fp16 (8 elems/thread)
// blocks [HID_BLOCKS, HID_BLOCKS+W1_BLOCKS): w1 -> bfrag fragment-pack +
//   logits init to b2.
// bfrag layout (EXACT MFMA B-fragment order):
//   flat f16 index fo = (((tt*48 + s)*2 + kc)*64 + lane)*8 + j
//   content: channel c = tt*16 + (lane&15)
//            k         = s*64 + kc*32 + ((lane>>4)<<3) + j   (k' = kk*1024+d)
// so a wave's per-step B fragment is one contiguous 1 KB global_load_dwordx4.
// ---------------------------------------------------------------------------
__global__ __launch_bounds__(256) void convert_all_kernel(
        const float* __restrict__ hidden, _Float16* __restrict__ hid16,
        const float* __restrict__ w1, const float* __restrict__ b2,
        _Float16* __restrict__ bfrag, float* __restrict__ logits) {
    if (blockIdx.x < HID_BLOCKS) {
        size_t idx = (size_t)blockIdx.x * 256 + threadIdx.x;
        float4 v0 = ((const float4*)hidden)[idx * 2];
        float4 v1 = ((const float4*)hidden)[idx * 2 + 1];
        f16x8 o;
        o[0] = (_Float16)v0.x; o[1] = (_Float16)v0.y;
        o[2] = (_Float16)v0.z; o[3] = (_Float16)v0.w;
        o[4] = (_Float16)v1.x; o[5] = (_Float16)v1.y;
        o[6] = (_Float16)v1.z; o[7] = (_Float16)v1.w;
        ((f16x8*)hid16)[idx] = o;
    } else {
        int idx = (blockIdx.x - HID_BLOCKS) * 256 + threadIdx.x;  // < 384*3072
        int j = idx & 7;
        int lane = (idx >> 3) & 63;
        int kc = (idx >> 9) & 1;
        int rest = idx >> 10;
        int s = rest % KSTEPS;
        int tt = rest / KSTEPS;
        int c = tt * 16 + (lane & 15);
        int k = s * 64 + kc * 32 + ((lane >> 4) << 3) + j;
        int kk = k >> 10, d = k & 1023;
        float v = (c < CH) ? w1[((size_t)c * 1024 + d) * 3 + kk] : 0.0f;
        bfrag[idx] = (_Float16)v;
        if (idx < B_SZ * LCONV) logits[idx] = b2[0];
    }
}

// ---------------------------------------------------------------------------
// fp16 MFMA conv GEMM, B-in-registers (R2 configuration — measured best at
// 57.8-58 us across R2/R3/R4/R7/R8; frozen at this empirical optimum).
// Tile 64 l x 192 c, BK=64, 4 waves (1x4), wave-tile 64x48 (4x3 of 16x16x32)
// -> 24 MFMAs per step per wave. B loaded per step straight into registers
// from fragment-ordered bfrag, prefetched one step ahead; A double-buffered
// in LDS via gl_lds16 (16 KB). Grid (2,32,8) = 512 blocks = 2/CU.
// Fused epilogue: relu(h+b1)*w2 reduced over c, atomicAdd into logits.
// ---------------------------------------------------------------------------
#define LDS_BUF 8192         // byte offset between the two A buffers

__global__ __launch_bounds__(256, 2) void conv_mfma_kernel(
        const _Float16* __restrict__ hid16, const _Float16* __restrict__ bfrag,
        const float* __restrict__ b1, const float* __restrict__ w2,
        float* __restrict__ logits) {
    const int nt = blockIdx.x;           // 0..1
    const int mt = blockIdx.y;           // 0..31
    const int b  = blockIdx.z;
    const int l0 = mt * 64;
    const int n0 = nt * 192;
    const int tid = threadIdx.x;
    const int wave = tid >> 6, lane = tid & 63;
    const int wn = wave;                 // 1x4 wave grid: wave = channel strip
    const int quad = lane >> 4, l16 = lane & 15;

    __shared__ __align__(16) char lds[2 * LDS_BUF];   // 16 KB: 2 x A 8K

    const _Float16* hb = hid16 + (size_t)b * L_SZ * D_SZ;

    // A staging source pointers: 512 entries (2 kc x 256), 2 per thread.
    // entry e (within kc): i=e>>6 (row block), m=i*16+(e&15), koff=((e>>4)&3)*8
    const _Float16* pa[2];
    #pragma unroll
    for (int p = 0; p < 2; ++p) {
        int f = p * 256 + tid;
        int kc = f >> 8, e = f & 255;
        int m = ((e >> 6) << 4) + (e & 15);
        int koff = ((e >> 4) & 3) * 8;
        int l = l0 + m; if (l > LCONV - 1) l = LCONV - 1;
        pa[p] = hb + (size_t)l * 1024 + kc * 32 + koff;
    }

    // B fragment pointers: one per jj, advancing 128 f16x8-units (2 KB) / step.
    // Fragment (tt, s, kc) lives at f16x8-unit index ((tt*48+s)*2+kc)*64 + lane.
    const f16x8* bp = (const f16x8*)bfrag;
    const f16x8* bptr[3];
    #pragma unroll
    for (int jj = 0; jj < 3; ++jj) {
        int tt = nt * 12 + wn * 3 + jj;
        bptr[jj] = bp + (size_t)tt * (KSTEPS * 2 * 64) + lane;
    }

    f32x4 acc[4][3] = {};
    f16x8 bc[3][2], bn[3][2];

    // ---- prologue: B step 0 into regs, A step 0 into buffer 0 ----
    #pragma unroll
    for (int jj = 0; jj < 3; ++jj)
        #pragma unroll
        for (int kc = 0; kc < 2; ++kc)
            bc[jj][kc] = bptr[jj][kc * 64];
    #pragma unroll
    for (int jj = 0; jj < 3; ++jj) bptr[jj] += 128;
    #pragma unroll
    for (int p = 0; p < 2; ++p)
        gl_lds16(pa[p], lds + (p * 256 + wave * 64) * 16);
    #pragma unroll
    for (int p = 0; p < 2; ++p) pa[p] += 64;
    __syncthreads();          // buffer 0 + bc ready

    int cur = 0;
    for (int s = 0; s < KSTEPS - 1; ++s) {
        const int nxt = cur ^ LDS_BUF;
        // prefetch B step s+1 into regs (consumed next iter; completes by barrier)
        #pragma unroll
        for (int jj = 0; jj < 3; ++jj)
            #pragma unroll
            for (int kc = 0; kc < 2; ++kc)
                bn[jj][kc] = bptr[jj][kc * 64];
        #pragma unroll
        for (int jj = 0; jj < 3; ++jj) bptr[jj] += 128;
        // prefetch A step s+1 into other LDS buffer
        #pragma unroll
        for (int p = 0; p < 2; ++p)
            gl_lds16(pa[p], lds + nxt + (p * 256 + wave * 64) * 16);
        #pragma unroll
        for (int p = 0; p < 2; ++p) pa[p] += 64;

        // compute step s from cur + bc
        #pragma unroll
        for (int kc = 0; kc < 2; ++kc) {
            f16x8 a[4];
            #pragma unroll
            for (int ii = 0; ii < 4; ++ii)
                a[ii] = *(const f16x8*)(lds + cur + (kc * 256 + ii * 64 + lane) * 16);
            #pragma unroll
            for (int ii = 0; ii < 4; ++ii)
                #pragma unroll
                for (int jj = 0; jj < 3; ++jj)
                    acc[ii][jj] = __builtin_amdgcn_mfma_f32_16x16x32_f16(
                        a[ii], bc[jj][kc], acc[ii][jj], 0, 0, 0);
        }
        __syncthreads();      // vmcnt(0): A nxt + B s+1 landed; cur reads done
        #pragma unroll
        for (int jj = 0; jj < 3; ++jj)
            #pragma unroll
            for (int kc = 0; kc < 2; ++kc)
                bc[jj][kc] = bn[jj][kc];
        cur = nxt;
    }
    // final step (no prefetch)
    #pragma unroll
    for (int kc = 0; kc < 2; ++kc) {
        f16x8 a[4];
        #pragma unroll
        for (int ii = 0; ii < 4; ++ii)
            a[ii] = *(const f16x8*)(lds + cur + (kc * 256 + ii * 64 + lane) * 16);
        #pragma unroll
        for (int ii = 0; ii < 4; ++ii)
            #pragma unroll
            for (int jj = 0; jj < 3; ++jj)
                acc[ii][jj] = __builtin_amdgcn_mfma_f32_16x16x32_f16(
                    a[ii], bc[jj][kc], acc[ii][jj], 0, 0, 0);
    }
    __syncthreads();          // before reusing lds as reduction scratch

    // --- epilogue: relu(acc + b1)*w2, reduce over c, atomic into logits ---
    float cb1[3], cw2[3];
    #pragma unroll
    for (int jj = 0; jj < 3; ++jj) {
        int ch = n0 + wn * 48 + jj * 16 + l16;
        bool v = ch < CH;
        cb1[jj] = v ? b1[ch] : 0.0f;
        cw2[jj] = v ? w2[ch] : 0.0f;
    }
    float* red = (float*)lds;   // [64][4]
    #pragma unroll
    for (int ii = 0; ii < 4; ++ii)
        #pragma unroll
        for (int r = 0; r < 4; ++r) {
            float P = 0.0f;
            #pragma unroll
            for (int jj = 0; jj < 3; ++jj) {
                float h = acc[ii][jj][r] + cb1[jj];
                if (h > 0.0f) P += h * cw2[jj];
            }
            P += __shfl_xor(P, 1);
            P += __shfl_xor(P, 2);
            P += __shfl_xor(P, 4);
            P += __shfl_xor(P, 8);
            if (l16 == 0)
                red[(ii * 16 + quad * 4 + r) * 4 + wn] = P;
        }
    __syncthreads();
    if (tid < 64) {
        int l = l0 + tid;
        if (l < LCONV)
            atomicAdd(&logits[b * LCONV + l],
                      red[tid * 4] + red[tid * 4 + 1] + red[tid * 4 + 2] + red[tid * 4 + 3]);
    }
}

// ---------------------------------------------------------------------------
// Fused fixup + boundary scan (1 dispatch instead of 2, and corrected
// logits live only in LDS — no global round-trip).
// Block b: stage logits[b] into LDS -> flag |v|<0.02 (expected ~0.4 total
// pipeline-wide; >>50 sigma of the fp16 GEMM error) -> exact fp32 recompute
// of flagged in-LDS -> hard bits -> prefix scan -> segstart/segid/short_mask
// -> per-batch (total,len) to scratch (summed by pool_gather; no memset).
// ---------------------------------------------------------------------------
__global__ __launch_bounds__(256) void scanfix_kernel(
        const float* __restrict__ logits, const float* __restrict__ amask,
        const float* __restrict__ hidden, const float* __restrict__ w1,
        const float* __restrict__ b1, const float* __restrict__ w2,
        const float* __restrict__ b2,
        int* __restrict__ segstart, int* __restrict__ segid,
        float* __restrict__ scratch, float* __restrict__ short_mask) {
    const int b = blockIdx.x, tid = threadIdx.x;
    __shared__ float slog[2048];
    __shared__ float hrow[3 * 1024];
    __shared__ int sdata[256];
    __shared__ float sred[256];
    __shared__ int flags[64];
    __shared__ int nflag;
    __shared__ int s_len, s_total;

    // stage logits into LDS
    for (int t = tid; t < LCONV; t += 256)
        slog[t] = logits[b * LCONV + t];
    if (tid == 0) nflag = 0;

    // len = sum(amask[b])
    int cnt = 0;
    #pragma unroll
    for (int j = 0; j < 8; ++j) {
        int l = tid * 8 + j;
        cnt += (amask[b * L_SZ + l] > 0.5f) ? 1 : 0;
    }
    sdata[tid] = cnt; __syncthreads();
    for (int off = 128; off > 0; off >>= 1) {
        if (tid < off) sdata[tid] += sdata[tid + off];
        __syncthreads();
    }
    if (tid == 0) s_len = sdata[0];
    __syncthreads();
    const int len = s_len;

    // ---- fixup phase: flag near-zero logits, recompute exactly in LDS ----
    for (int t = tid; t < LCONV; t += 256)
        if (fabsf(slog[t]) < 0.02f) {
            int k = atomicAdd(&nflag, 1);
            if (k < 64) flags[k] = t;
        }
    __syncthreads();
    const int nf = (nflag < 64) ? nflag : 64;
    for (int fi = 0; fi < nf; ++fi) {
        const int l = flags[fi];
        for (int t = tid; t < 3072; t += 256)
            hrow[t] = hidden[((size_t)b * L_SZ + l) * 1024 + t];
        __syncthreads();
        float tot = 0.0f;
        for (int c = tid; c < CH; c += 256) {
            const float* wr = w1 + (size_t)c * 3072;
            float dot = 0.0f;
            for (int d = 0; d < 1024; ++d)
                dot += hrow[d] * wr[d * 3] + hrow[1024 + d] * wr[d * 3 + 1]
                     + hrow[2048 + d] * wr[d * 3 + 2];
            float h = dot + b1[c];
            if (h > 0.0f) tot += h * w2[c];
        }
        sred[tid] = tot; __syncthreads();
        for (int off = 128; off > 0; off >>= 1) {
            if (tid < off) sred[tid] += sred[tid + off];
            __syncthreads();
        }
        if (tid == 0) slog[l] = sred[0] + b2[0];
        __syncthreads();
    }

    // ---- scan phase (bits from corrected LDS logits) ----
    int bits[8]; int tsum = 0;
    #pragma unroll
    for (int j = 0; j < 8; ++j) {
        int l = tid * 8 + j;
        int h = 0;
        if (l >= 2 && l < len) h = (slog[l - 2] > 0.0f) ? 1 : 0;
        if (len < L_SZ && l == len - 1) h = 1;
        bits[j] = h; tsum += h;
    }
    __syncthreads();
    sdata[tid] = tsum; __syncthreads();
    for (int off = 1; off < 256; off <<= 1) {
        int v = (tid >= off) ? sdata[tid - off] : 0;
        __syncthreads();
        sdata[tid] += v;
        __syncthreads();
    }
    const int texcl = sdata[tid] - tsum;
    if (tid == 255) s_total = sdata[255];
    __syncthreads();
    const int total = s_total;

    for (int s = tid; s <= NSEG; s += 256)
        segstart[b * (NSEG + 1) + s] = (s == 0) ? 0 : len;
    __syncthreads();
    int run = texcl;
    #pragma unroll
    for (int j = 0; j < 8; ++j) {
        int l = tid * 8 + j;
        int sv = -1;
        if (l < len && run < NSEG) sv = run;
        segid[b * L_SZ + l] = sv;
        if (bits[j]) {
            if (run + 1 <= NSEG) segstart[b * (NSEG + 1) + run + 1] = l + 1;
            run++;
        }
    }

    if (tid == 0) {
        scratch[b] = (float)total;       // summed by pool_gather (no memset)
        scratch[B_SZ + b] = (float)len;
    }
    for (int s = tid; s < NSEG; s += 256)
        short_mask[b * NSEG + s] = (s < total) ? 1.0f : 0.0f;
}

// ---------------------------------------------------------------------------
// Pool phase 1: contention-free chunk partials via the monotone-segid slot
// trick. Run r of chunk c with segment id s stores at slot (c + s):
// injective across all (chunk, run) pairs because segid is non-decreasing,
// and segment s's contributions occupy CONTIGUOUS slots [c0+s, c1+s].
// Plain float4 stores — no atomics. Grid (128,8) x 256 (token-parallel).
// ---------------------------------------------------------------------------
__global__ __launch_bounds__(256) void pool_partial_kernel(
        const float* __restrict__ hidden, const int* __restrict__ segid,
        float* __restrict__ runsum) {
    const int c = blockIdx.x, b = blockIdx.y;
    const int tid = threadIdx.x;
    const int d0 = tid * 4;
    const int lbase = c * 16;
    const float* hb = hidden + (size_t)b * L_SZ * D_SZ + d0;
    const int* sg = segid + b * L_SZ + lbase;
    float* rb = runsum + ((size_t)(b * NSLOT + c)) * D_SZ + d0;  // slot c+sid
    float4 acc = make_float4(0.f, 0.f, 0.f, 0.f);
    int cur = -1;
    #pragma unroll
    for (int t = 0; t < 16; ++t) {
        int sid = sg[t];
        if (sid != cur) {
            if (cur >= 0)
                *(float4*)(rb + (size_t)cur * D_SZ) = acc;
            acc = make_float4(0.f, 0.f, 0.f, 0.f);
            cur = sid;
        }
        if (sid >= 0) {
            float4 v = *(const float4*)(hb + (size_t)(lbase + t) * D_SZ);
            acc.x += v.x; acc.y += v.y; acc.z += v.z; acc.w += v.w;
        }
    }
    if (cur >= 0)
        *(float4*)(rb + (size_t)cur * D_SZ) = acc;
}

// ---------------------------------------------------------------------------
// Pool phase 2 (fused finalize): block (s,b) sums segment s's contiguous
// runsum slots [c0+s, c1+s], divides by count, adds sinusoidal PE, writes
// pooled once. Block (0,0) also finalizes nb/tp from scratch.
// Empty segment: acc=0 -> 0*inv + PE (matches ref). No pooled memset.
// ---------------------------------------------------------------------------
__global__ __launch_bounds__(256) void pool_gather_kernel(
        const float* __restrict__ runsum, const int* __restrict__ segstart,
        const float* __restrict__ scratch, float* __restrict__ pooled,
        float* __restrict__ out_nb, float* __restrict__ out_tp) {
    const int s = blockIdx.x, b = blockIdx.y, tid = threadIdx.x;
    if (s == 0 && b == 0 && tid == 0) {
        float nb = 0.f, tp = 0.f;
        #pragma unroll
        for (int i = 0; i < B_SZ; ++i) { nb += scratch[i]; tp += scratch[B_SZ + i]; }
        *out_nb = nb; *out_tp = tp;
    }
    const int l0 = segstart[b * (NSEG + 1) + s];
    const int l1 = segstart[b * (NSEG + 1) + s + 1];
    const int d0 = tid * 4;
    float4 a0 = make_float4(0.f, 0.f, 0.f, 0.f);
    float4 a1 = make_float4(0.f, 0.f, 0.f, 0.f);
    if (l1 > l0) {
        const int c0 = l0 >> 4, c1 = (l1 - 1) >> 4;
        const float* rs = runsum + ((size_t)(b * NSLOT + s)) * D_SZ + d0;
        int c = c0;
        for (; c + 1 <= c1; c += 2) {
            float4 v0 = *(const float4*)(rs + (size_t)c * D_SZ);
            float4 v1 = *(const float4*)(rs + (size_t)(c + 1) * D_SZ);
            a0.x += v0.x; a0.y += v0.y; a0.z += v0.z; a0.w += v0.w;
            a1.x += v1.x; a1.y += v1.y; a1.z += v1.z; a1.w += v1.w;
        }
        if (c <= c1) {
            float4 v0 = *(const float4*)(rs + (size_t)c * D_SZ);
            a0.x += v0.x; a0.y += v0.y; a0.z += v0.z; a0.w += v0.w;
        }
    }
    const float inv = 1.0f / ((float)(l1 - l0) + 1e-9f);
    const float ce = -9.210340371976184f / 512.0f;
    const int i = d0 >> 1;
    const float t0 = (float)s * expf(ce * (float)i);
    const float t1 = (float)s * expf(ce * (float)(i + 1));
    float4 out;
    out.x = (a0.x + a1.x) * inv + sinf(t0);
    out.y = (a0.y + a1.y) * inv + cosf(t0);
    out.z = (a0.z + a1.z) * inv + sinf(t1);
    out.w = (a0.w + a1.w) * inv + cosf(t1);
    *(float4*)(pooled + ((size_t)(b * NSEG + s)) * D_SZ + d0) = out;
}

// ---------------------------------------------------------------------------
extern "C" void kernel_launch(void* const* d_in, const int* in_sizes, int n_in,
                              void* d_out, int out_size, void* d_ws, size_t ws_size,
                              hipStream_t stream) {
    const float* hidden = (const float*)d_in[0];
    const float* amask  = (const float*)d_in[1];
    const float* w1     = (const float*)d_in[2];
    const float* b1     = (const float*)d_in[3];
    const float* w2     = (const float*)d_in[4];
    const float* b2     = (const float*)d_in[5];

    float* out    = (float*)d_out;
    float* pooled = out;
    float* nb     = out + POOLED_N;
    float* tp     = nb + 1;
    float* smask  = out + POOLED_N + 2;

    const size_t HID_E = (size_t)B_SZ * L_SZ * D_SZ;           // 16,777,216
    const size_t OFF_HID16    = 0;
    const size_t OFF_BPACK    = OFF_HID16 + HID_E * 2;                 // 32 MB
    const size_t OFF_LOGITS   = OFF_BPACK + (size_t)CP * KDIM * 2;     // +2.25 MB
    const size_t OFF_SEGSTART = OFF_LOGITS + (size_t)B_SZ * LCONV * 4;
    const size_t OFF_SEGID    = OFF_SEGSTART + (size_t)B_SZ * (NSEG + 1) * 4;
    const size_t OFF_SCRATCH  = OFF_SEGID + (size_t)B_SZ * L_SZ * 4;

    _Float16* hid16  = (_Float16*)((char*)d_ws + OFF_HID16);
    _Float16* bfrag  = (_Float16*)((char*)d_ws + OFF_BPACK);
    float*    logits = (float*)((char*)d_ws + OFF_LOGITS);
    int*      segst  = (int*)((char*)d_ws + OFF_SEGSTART);
    int*      segid  = (int*)((char*)d_ws + OFF_SEGID);
    float*    scratch= (float*)((char*)d_ws + OFF_SCRATCH);
    // runsum (8 x 640 x 1024 fp32 = 20 MB) OVERLAYS hid16 (32 MB): hid16 is
    // dead after conv_mfma; pool_partial runs strictly later on the stream.
    float*    runsum = (float*)((char*)d_ws + OFF_HID16);

    convert_all_kernel<<<HID_BLOCKS + W1_BLOCKS, 256, 0, stream>>>(
        hidden, hid16, w1, b2, bfrag, logits);
    conv_mfma_kernel<<<dim3(2, 32, B_SZ), 256, 0, stream>>>(hid16, bfrag, b1, w2, logits);
    scanfix_kernel<<<B_SZ, 256, 0, stream>>>(logits, amask, hidden, w1, b1, w2, b2,
                                             segst, segid, scratch, smask);
    pool_partial_kernel<<<dim3(NCHUNK, B_SZ), 256, 0, stream>>>(hidden, segid, runsum);
    pool_gather_kernel<<<dim3(NSEG, B_SZ), 256, 0, stream>>>(runsum, segst, scratch,
                                                             pooled, nb, tp);
}

// Round 10
// 196.832 us; speedup vs baseline: 3.7018x; 1.0329x over previous
//
#include <hip/hip_runtime.h>
#include <hip/hip_bf16.h>
#include <cmath>

// Problem constants
#define B_SZ 8
#define L_SZ 2048
#define D_SZ 1024
#define CH 341
#define CP 384               // padded channel dim (24 x 16)
#define LCONV 2046           // L - KERNEL + 1
#define NSEG 512
#define KDIM 3072            // 3 * 1024 folded conv K
#define KSTEPS 48            // KDIM / 64
#define NCHUNK 128           // 16-token chunks per batch
#define W1XB 576             // w1-pack x-blocks per batch slice (576*8*256 = 384*3072)

#define POOLED_N (B_SZ * NSEG * D_SZ)

typedef _Float16 f16x8 __attribute__((ext_vector_type(8)));
typedef _Float16 f16x4 __attribute__((ext_vector_type(4)));
typedef float f32x4 __attribute__((ext_vector_type(4)));

__device__ __forceinline__ void gl_lds16(const void* g, void* l) {
    __builtin_amdgcn_global_load_lds(
        (const __attribute__((address_space(1))) unsigned int*)g,
        (__attribute__((address_space(3))) unsigned int*)l, 16, 0, 0);
}

// ---------------------------------------------------------------------------
// Fused converts + chunk sums:
// blocks x<NCHUNK (per b): convert 16 hidden rows fp32->fp16 AND accumulate
//   the chunk row-sum (boundary-independent pooling partial — replaces the
//   pool_partial kernel's second 64 MB read of hidden; +48 VALU adds/thread,
//   zero extra traffic).
// blocks x>=NCHUNK: w1 -> bfrag fragment-pack + logits init to b2.
// bfrag layout (EXACT MFMA B-fragment order):
//   flat f16 index fo = (((tt*48 + s)*2 + kc)*64 + lane)*8 + j
//   content: channel c = tt*16 + (lane&15)
//            k         = s*64 + kc*32 + ((lane>>4)<<3) + j   (k' = kk*1024+d)
// ---------------------------------------------------------------------------
__global__ __launch_bounds__(256) void convert_all_kernel(
        const float* __restrict__ hidden, _Float16* __restrict__ hid16,
        const float* __restrict__ w1, const float* __restrict__ b2,
        _Float16* __restrict__ bfrag, float* __restrict__ logits,
        float* __restrict__ chunksum) {
    const int bx = blockIdx.x, b = blockIdx.y;
    const int tid = threadIdx.x;
    if (bx < NCHUNK) {
        const int d0 = tid * 4;
        const float* src = hidden + ((size_t)b * L_SZ + bx * 16) * D_SZ + d0;
        _Float16* dst = hid16 + ((size_t)b * L_SZ + bx * 16) * D_SZ + d0;
        float4 acc = make_float4(0.f, 0.f, 0.f, 0.f);
        #pragma unroll
        for (int r = 0; r < 16; ++r) {
            float4 v = *(const float4*)(src + (size_t)r * D_SZ);
            acc.x += v.x; acc.y += v.y; acc.z += v.z; acc.w += v.w;
            f16x4 o;
            o[0] = (_Float16)v.x; o[1] = (_Float16)v.y;
            o[2] = (_Float16)v.z; o[3] = (_Float16)v.w;
            *(f16x4*)(dst + (size_t)r * D_SZ) = o;
        }
        *(float4*)(chunksum + ((size_t)(b * NCHUNK + bx)) * D_SZ + d0) = acc;
    } else {
        int idx = (((bx - NCHUNK) * B_SZ) + b) * 256 + tid;   // bijective < 384*3072
        int j = idx & 7;
        int lane = (idx >> 3) & 63;
        int kc = (idx >> 9) & 1;
        int rest = idx >> 10;
        int s = rest % KSTEPS;
        int tt = rest / KSTEPS;
        int c = tt * 16 + (lane & 15);
        int k = s * 64 + kc * 32 + ((lane >> 4) << 3) + j;
        int kk = k >> 10, d = k & 1023;
        float v = (c < CH) ? w1[((size_t)c * 1024 + d) * 3 + kk] : 0.0f;
        bfrag[idx] = (_Float16)v;
        if (idx < B_SZ * LCONV) logits[idx] = b2[0];
    }
}

// ---------------------------------------------------------------------------
// fp16 MFMA conv GEMM, B-in-registers (R2 configuration — measured best at
// 57.8-60 us across R2/R3/R4/R7/R8/R9; frozen at this empirical optimum).
// Tile 64 l x 192 c, BK=64, 4 waves (1x4), wave-tile 64x48 (4x3 of 16x16x32)
// -> 24 MFMAs per step per wave. B loaded per step straight into registers
// from fragment-ordered bfrag, prefetched one step ahead; A double-buffered
// in LDS via gl_lds16 (16 KB). Grid (2,32,8) = 512 blocks = 2/CU.
// Fused epilogue: relu(h+b1)*w2 reduced over c, atomicAdd into logits.
// ---------------------------------------------------------------------------
#define LDS_BUF 8192         // byte offset between the two A buffers

__global__ __launch_bounds__(256, 2) void conv_mfma_kernel(
        const _Float16* __restrict__ hid16, const _Float16* __restrict__ bfrag,
        const float* __restrict__ b1, const float* __restrict__ w2,
        float* __restrict__ logits) {
    const int nt = blockIdx.x;           // 0..1
    const int mt = blockIdx.y;           // 0..31
    const int b  = blockIdx.z;
    const int l0 = mt * 64;
    const int n0 = nt * 192;
    const int tid = threadIdx.x;
    const int wave = tid >> 6, lane = tid & 63;
    const int wn = wave;                 // 1x4 wave grid: wave = channel strip
    const int quad = lane >> 4, l16 = lane & 15;

    __shared__ __align__(16) char lds[2 * LDS_BUF];   // 16 KB: 2 x A 8K

    const _Float16* hb = hid16 + (size_t)b * L_SZ * D_SZ;

    // A staging source pointers: 512 entries (2 kc x 256), 2 per thread.
    // entry e (within kc): i=e>>6 (row block), m=i*16+(e&15), koff=((e>>4)&3)*8
    const _Float16* pa[2];
    #pragma unroll
    for (int p = 0; p < 2; ++p) {
        int f = p * 256 + tid;
        int kc = f >> 8, e = f & 255;
        int m = ((e >> 6) << 4) + (e & 15);
        int koff = ((e >> 4) & 3) * 8;
        int l = l0 + m; if (l > LCONV - 1) l = LCONV - 1;
        pa[p] = hb + (size_t)l * 1024 + kc * 32 + koff;
    }

    // B fragment pointers: one per jj, advancing 128 f16x8-units (2 KB) / step.
    // Fragment (tt, s, kc) lives at f16x8-unit index ((tt*48+s)*2+kc)*64 + lane.
    const f16x8* bp = (const f16x8*)bfrag;
    const f16x8* bptr[3];
    #pragma unroll
    for (int jj = 0; jj < 3; ++jj) {
        int tt = nt * 12 + wn * 3 + jj;
        bptr[jj] = bp + (size_t)tt * (KSTEPS * 2 * 64) + lane;
    }

    f32x4 acc[4][3] = {};
    f16x8 bc[3][2], bn[3][2];

    // ---- prologue: B step 0 into regs, A step 0 into buffer 0 ----
    #pragma unroll
    for (int jj = 0; jj < 3; ++jj)
        #pragma unroll
        for (int kc = 0; kc < 2; ++kc)
            bc[jj][kc] = bptr[jj][kc * 64];
    #pragma unroll
    for (int jj = 0; jj < 3; ++jj) bptr[jj] += 128;
    #pragma unroll
    for (int p = 0; p < 2; ++p)
        gl_lds16(pa[p], lds + (p * 256 + wave * 64) * 16);
    #pragma unroll
    for (int p = 0; p < 2; ++p) pa[p] += 64;
    __syncthreads();          // buffer 0 + bc ready

    int cur = 0;
    for (int s = 0; s < KSTEPS - 1; ++s) {
        const int nxt = cur ^ LDS_BUF;
        // prefetch B step s+1 into regs (consumed next iter; completes by barrier)
        #pragma unroll
        for (int jj = 0; jj < 3; ++jj)
            #pragma unroll
            for (int kc = 0; kc < 2; ++kc)
                bn[jj][kc] = bptr[jj][kc * 64];
        #pragma unroll
        for (int jj = 0; jj < 3; ++jj) bptr[jj] += 128;
        // prefetch A step s+1 into other LDS buffer
        #pragma unroll
        for (int p = 0; p < 2; ++p)
            gl_lds16(pa[p], lds + nxt + (p * 256 + wave * 64) * 16);
        #pragma unroll
        for (int p = 0; p < 2; ++p) pa[p] += 64;

        // compute step s from cur + bc
        #pragma unroll
        for (int kc = 0; kc < 2; ++kc) {
            f16x8 a[4];
            #pragma unroll
            for (int ii = 0; ii < 4; ++ii)
                a[ii] = *(const f16x8*)(lds + cur + (kc * 256 + ii * 64 + lane) * 16);
            #pragma unroll
            for (int ii = 0; ii < 4; ++ii)
                #pragma unroll
                for (int jj = 0; jj < 3; ++jj)
                    acc[ii][jj] = __builtin_amdgcn_mfma_f32_16x16x32_f16(
                        a[ii], bc[jj][kc], acc[ii][jj], 0, 0, 0);
        }
        __syncthreads();      // vmcnt(0): A nxt + B s+1 landed; cur reads done
        #pragma unroll
        for (int jj = 0; jj < 3; ++jj)
            #pragma unroll
            for (int kc = 0; kc < 2; ++kc)
                bc[jj][kc] = bn[jj][kc];
        cur = nxt;
    }
    // final step (no prefetch)
    #pragma unroll
    for (int kc = 0; kc < 2; ++kc) {
        f16x8 a[4];
        #pragma unroll
        for (int ii = 0; ii < 4; ++ii)
            a[ii] = *(const f16x8*)(lds + cur + (kc * 256 + ii * 64 + lane) * 16);
        #pragma unroll
        for (int ii = 0; ii < 4; ++ii)
            #pragma unroll
            for (int jj = 0; jj < 3; ++jj)
                acc[ii][jj] = __builtin_amdgcn_mfma_f32_16x16x32_f16(
                    a[ii], bc[jj][kc], acc[ii][jj], 0, 0, 0);
    }
    __syncthreads();          // before reusing lds as reduction scratch

    // --- epilogue: relu(acc + b1)*w2, reduce over c, atomic into logits ---
    float cb1[3], cw2[3];
    #pragma unroll
    for (int jj = 0; jj < 3; ++jj) {
        int ch = n0 + wn * 48 + jj * 16 + l16;
        bool v = ch < CH;
        cb1[jj] = v ? b1[ch] : 0.0f;
        cw2[jj] = v ? w2[ch] : 0.0f;
    }
    float* red = (float*)lds;   // [64][4]
    #pragma unroll
    for (int ii = 0; ii < 4; ++ii)
        #pragma unroll
        for (int r = 0; r < 4; ++r) {
            float P = 0.0f;
            #pragma unroll
            for (int jj = 0; jj < 3; ++jj) {
                float h = acc[ii][jj][r] + cb1[jj];
                if (h > 0.0f) P += h * cw2[jj];
            }
            P += __shfl_xor(P, 1);
            P += __shfl_xor(P, 2);
            P += __shfl_xor(P, 4);
            P += __shfl_xor(P, 8);
            if (l16 == 0)
                red[(ii * 16 + quad * 4 + r) * 4 + wn] = P;
        }
    __syncthreads();
    if (tid < 64) {
        int l = l0 + tid;
        if (l < LCONV)
            atomicAdd(&logits[b * LCONV + l],
                      red[tid * 4] + red[tid * 4 + 1] + red[tid * 4 + 2] + red[tid * 4 + 3]);
    }
}

// ---------------------------------------------------------------------------
// Fused fixup + boundary scan + chunk-prefix.
// Block b: stage logits[b] into LDS -> flag |v|<0.02 -> exact fp32 recompute
// of flagged in-LDS (expected ~0.4 flagged pipeline-wide) -> hard bits ->
// prefix scan -> segstart/short_mask -> per-batch (total,len) to scratch.
// Then: exclusive prefix P[b][c] over the 128 chunk sums (4-unrolled walk,
// ~3 us across 8 blocks) for the prefix-difference pooling in pool_gather.
// segid is GONE (pool_partial eliminated).
// ---------------------------------------------------------------------------
__global__ __launch_bounds__(256) void scanfix_kernel(
        const float* __restrict__ logits, const float* __restrict__ amask,
        const float* __restrict__ hidden, const float* __restrict__ w1,
        const float* __restrict__ b1, const float* __restrict__ w2,
        const float* __restrict__ b2,
        int* __restrict__ segstart, float* __restrict__ scratch,
        float* __restrict__ short_mask,
        const float* __restrict__ chunksum, float* __restrict__ prefix) {
    const int b = blockIdx.x, tid = threadIdx.x;
    __shared__ float slog[2048];
    __shared__ float hrow[3 * 1024];
    __shared__ int sdata[256];
    __shared__ float sred[256];
    __shared__ int flags[64];
    __shared__ int nflag;
    __shared__ int s_len, s_total;

    // stage logits into LDS
    for (int t = tid; t < LCONV; t += 256)
        slog[t] = logits[b * LCONV + t];
    if (tid == 0) nflag = 0;

    // len = sum(amask[b])
    int cnt = 0;
    #pragma unroll
    for (int j = 0; j < 8; ++j) {
        int l = tid * 8 + j;
        cnt += (amask[b * L_SZ + l] > 0.5f) ? 1 : 0;
    }
    sdata[tid] = cnt; __syncthreads();
    for (int off = 128; off > 0; off >>= 1) {
        if (tid < off) sdata[tid] += sdata[tid + off];
        __syncthreads();
    }
    if (tid == 0) s_len = sdata[0];
    __syncthreads();
    const int len = s_len;

    // ---- fixup phase: flag near-zero logits, recompute exactly in LDS ----
    for (int t = tid; t < LCONV; t += 256)
        if (fabsf(slog[t]) < 0.02f) {
            int k = atomicAdd(&nflag, 1);
            if (k < 64) flags[k] = t;
        }
    __syncthreads();
    const int nf = (nflag < 64) ? nflag : 64;
    for (int fi = 0; fi < nf; ++fi) {
        const int l = flags[fi];
        for (int t = tid; t < 3072; t += 256)
            hrow[t] = hidden[((size_t)b * L_SZ + l) * 1024 + t];
        __syncthreads();
        float tot = 0.0f;
        for (int c = tid; c < CH; c += 256) {
            const float* wr = w1 + (size_t)c * 3072;
            float dot = 0.0f;
            for (int d = 0; d < 1024; ++d)
                dot += hrow[d] * wr[d * 3] + hrow[1024 + d] * wr[d * 3 + 1]
                     + hrow[2048 + d] * wr[d * 3 + 2];
            float h = dot + b1[c];
            if (h > 0.0f) tot += h * w2[c];
        }
        sred[tid] = tot; __syncthreads();
        for (int off = 128; off > 0; off >>= 1) {
            if (tid < off) sred[tid] += sred[tid + off];
            __syncthreads();
        }
        if (tid == 0) slog[l] = sred[0] + b2[0];
        __syncthreads();
    }

    // ---- scan phase (bits from corrected LDS logits) ----
    int bits[8]; int tsum = 0;
    #pragma unroll
    for (int j = 0; j < 8; ++j) {
        int l = tid * 8 + j;
        int h = 0;
        if (l >= 2 && l < len) h = (slog[l - 2] > 0.0f) ? 1 : 0;
        if (len < L_SZ && l == len - 1) h = 1;
        bits[j] = h; tsum += h;
    }
    __syncthreads();
    sdata[tid] = tsum; __syncthreads();
    for (int off = 1; off < 256; off <<= 1) {
        int v = (tid >= off) ? sdata[tid - off] : 0;
        __syncthreads();
        sdata[tid] += v;
        __syncthreads();
    }
    const int texcl = sdata[tid] - tsum;
    if (tid == 255) s_total = sdata[255];
    __syncthreads();
    const int total = s_total;

    for (int s = tid; s <= NSEG; s += 256)
        segstart[b * (NSEG + 1) + s] = (s == 0) ? 0 : len;
    __syncthreads();
    int run = texcl;
    #pragma unroll
    for (int j = 0; j < 8; ++j) {
        int l = tid * 8 + j;
        if (bits[j]) {
            if (run + 1 <= NSEG) segstart[b * (NSEG + 1) + run + 1] = l + 1;
            run++;
        }
    }

    if (tid == 0) {
        scratch[b] = (float)total;       // summed by pool_gather (no memset)
        scratch[B_SZ + b] = (float)len;
    }
    for (int s = tid; s < NSEG; s += 256)
        short_mask[b * NSEG + s] = (s < total) ? 1.0f : 0.0f;

    // ---- chunk-prefix phase: exclusive prefix over 128 chunk sums ----
    {
        const int d0 = tid * 4;
        const float* cs = chunksum + ((size_t)b * NCHUNK) * D_SZ + d0;
        float* Pb = prefix + ((size_t)b * (NCHUNK + 1)) * D_SZ + d0;
        float4 p = make_float4(0.f, 0.f, 0.f, 0.f);
        *(float4*)Pb = p;
        for (int c = 0; c < NCHUNK; c += 4) {
            float4 v0 = *(const float4*)(cs + (size_t)c * D_SZ);
            float4 v1 = *(const float4*)(cs + (size_t)(c + 1) * D_SZ);
            float4 v2 = *(const float4*)(cs + (size_t)(c + 2) * D_SZ);
            float4 v3 = *(const float4*)(cs + (size_t)(c + 3) * D_SZ);
            p.x += v0.x; p.y += v0.y; p.z += v0.z; p.w += v0.w;
            *(float4*)(Pb + (size_t)(c + 1) * D_SZ) = p;
            p.x += v1.x; p.y += v1.y; p.z += v1.z; p.w += v1.w;
            *(float4*)(Pb + (size_t)(c + 2) * D_SZ) = p;
            p.x += v2.x; p.y += v2.y; p.z += v2.z; p.w += v2.w;
            *(float4*)(Pb + (size_t)(c + 3) * D_SZ) = p;
            p.x += v3.x; p.y += v3.y; p.z += v3.z; p.w += v3.w;
            *(float4*)(Pb + (size_t)(c + 4) * D_SZ) = p;
        }
    }
}

// ---------------------------------------------------------------------------
// Pool gather via prefix difference: sum[l0,l1) = P[cL]-P[cF] (full chunks
// cF..cL-1) + edge rows [l0, cF*16) + [cL*16, l1) read directly from hidden
// (<=30 rows/segment). Divide + sinusoidal PE fused; every element written
// -> no memset. Empty segment: a=0 -> 0*inv + PE. Block (0,0) finalizes
// nb/tp from scratch.
// ---------------------------------------------------------------------------
__global__ __launch_bounds__(256) void pool_gather_kernel(
        const float* __restrict__ hidden, const float* __restrict__ prefix,
        const int* __restrict__ segstart, const float* __restrict__ scratch,
        float* __restrict__ pooled,
        float* __restrict__ out_nb, float* __restrict__ out_tp) {
    const int s = blockIdx.x, b = blockIdx.y, tid = threadIdx.x;
    if (s == 0 && b == 0 && tid == 0) {
        float nb = 0.f, tp = 0.f;
        #pragma unroll
        for (int i = 0; i < B_SZ; ++i) { nb += scratch[i]; tp += scratch[B_SZ + i]; }
        *out_nb = nb; *out_tp = tp;
    }
    const int l0 = segstart[b * (NSEG + 1) + s];
    const int l1 = segstart[b * (NSEG + 1) + s + 1];
    const int d0 = tid * 4;
    float4 a = make_float4(0.f, 0.f, 0.f, 0.f);
    if (l1 > l0) {
        const int cF = (l0 + 15) >> 4;   // first full chunk
        const int cL = l1 >> 4;          // end (exclusive) of full chunks
        const float* hb = hidden + (size_t)b * L_SZ * D_SZ + d0;
        if (cL > cF) {
            const float* Pb = prefix + ((size_t)b * (NCHUNK + 1)) * D_SZ + d0;
            float4 pl = *(const float4*)(Pb + (size_t)cL * D_SZ);
            float4 pf = *(const float4*)(Pb + (size_t)cF * D_SZ);
            a.x = pl.x - pf.x; a.y = pl.y - pf.y;
            a.z = pl.z - pf.z; a.w = pl.w - pf.w;
            for (int l = l0; l < cF * 16; ++l) {
                float4 v = *(const float4*)(hb + (size_t)l * D_SZ);
                a.x += v.x; a.y += v.y; a.z += v.z; a.w += v.w;
            }
            for (int l = cL * 16; l < l1; ++l) {
                float4 v = *(const float4*)(hb + (size_t)l * D_SZ);
                a.x += v.x; a.y += v.y; a.z += v.z; a.w += v.w;
            }
        } else {
            for (int l = l0; l < l1; ++l) {
                float4 v = *(const float4*)(hb + (size_t)l * D_SZ);
                a.x += v.x; a.y += v.y; a.z += v.z; a.w += v.w;
            }
        }
    }
    const float inv = 1.0f / ((float)(l1 - l0) + 1e-9f);
    const float ce = -9.210340371976184f / 512.0f;
    const int i = d0 >> 1;
    const float t0 = (float)s * expf(ce * (float)i);
    const float t1 = (float)s * expf(ce * (float)(i + 1));
    float4 out;
    out.x = a.x * inv + sinf(t0);
    out.y = a.y * inv + cosf(t0);
    out.z = a.z * inv + sinf(t1);
    out.w = a.w * inv + cosf(t1);
    *(float4*)(pooled + ((size_t)(b * NSEG + s)) * D_SZ + d0) = out;
}

// ---------------------------------------------------------------------------
extern "C" void kernel_launch(void* const* d_in, const int* in_sizes, int n_in,
                              void* d_out, int out_size, void* d_ws, size_t ws_size,
                              hipStream_t stream) {
    const float* hidden = (const float*)d_in[0];
    const float* amask  = (const float*)d_in[1];
    const float* w1     = (const float*)d_in[2];
    const float* b1     = (const float*)d_in[3];
    const float* w2     = (const float*)d_in[4];
    const float* b2     = (const float*)d_in[5];

    float* out    = (float*)d_out;
    float* pooled = out;
    float* nb     = out + POOLED_N;
    float* tp     = nb + 1;
    float* smask  = out + POOLED_N + 2;

    const size_t HID_E = (size_t)B_SZ * L_SZ * D_SZ;           // 16,777,216
    const size_t OFF_HID16    = 0;
    const size_t OFF_BPACK    = OFF_HID16 + HID_E * 2;                 // 32 MB
    const size_t OFF_LOGITS   = OFF_BPACK + (size_t)CP * KDIM * 2;     // +2.25 MB
    const size_t OFF_SEGSTART = OFF_LOGITS + (size_t)B_SZ * LCONV * 4;
    const size_t OFF_SCRATCH  = OFF_SEGSTART + (size_t)B_SZ * (NSEG + 1) * 4;
    const size_t OFF_CHUNKSUM = OFF_SCRATCH + 1024;
    const size_t OFF_PREFIX   = OFF_CHUNKSUM + (size_t)B_SZ * NCHUNK * D_SZ * 4;

    _Float16* hid16   = (_Float16*)((char*)d_ws + OFF_HID16);
    _Float16* bfrag   = (_Float16*)((char*)d_ws + OFF_BPACK);
    float*    logits  = (float*)((char*)d_ws + OFF_LOGITS);
    int*      segst   = (int*)((char*)d_ws + OFF_SEGSTART);
    float*    scratch = (float*)((char*)d_ws + OFF_SCRATCH);
    float*    chsum   = (float*)((char*)d_ws + OFF_CHUNKSUM);
    float*    prefix  = (float*)((char*)d_ws + OFF_PREFIX);

    convert_all_kernel<<<dim3(NCHUNK + W1XB, B_SZ), 256, 0, stream>>>(
        hidden, hid16, w1, b2, bfrag, logits, chsum);
    conv_mfma_kernel<<<dim3(2, 32, B_SZ), 256, 0, stream>>>(hid16, bfrag, b1, w2, logits);
    scanfix_kernel<<<B_SZ, 256, 0, stream>>>(logits, amask, hidden, w1, b1, w2, b2,
                                             segst, scratch, smask, chsum, prefix);
    pool_gather_kernel<<<dim3(NSEG, B_SZ), 256, 0, stream>>>(hidden, prefix, segst,
                                                             scratch, pooled, nb, tp);
}